// Round 1
// 699.135 us; speedup vs baseline: 1.1424x; 1.1424x over previous
//
#include <hip/hip_runtime.h>

// Problem constants
constexpr int CH   = 128;    // C
constexpr int TWOC = 256;    // 2C
constexpr int NPTS = 32768;  // N
constexpr int NB   = 8;      // B
constexpr int KC   = 2048;   // K-chunk for fallback fp32 gram

// gram_mfma3 geometry
constexpr int KC3    = 1024; // K per block (32 chunks)
constexpr int KSTAGE = 128;  // K per LDS stage (256B per row burst)
constexpr int NST    = KC3 / KSTAGE;  // 8 stages
constexpr int NCHUNK = NPTS / KC3;    // 32

typedef _Float16 half8 __attribute__((ext_vector_type(8)));
typedef float floatx4 __attribute__((ext_vector_type(4)));

// ---------------- Workspace layout (float offsets) ----------------
constexpr size_t OFF_G  = 0;
constexpr size_t OFF_S  = 524288;
constexpr size_t OFF_P  = 526336;
constexpr size_t OFF_H  = 528384;
constexpr size_t OFF_E  = 1052672;
constexpr size_t OFF_E1 = 1576960;
constexpr size_t OFF_E2 = 2101248;
constexpr size_t OFF_AT = 2363392;
constexpr size_t OFF_C0 = 2625536;
constexpr size_t OFF_MH = 2626560;
constexpr size_t OFF_ZH = 2757632;
constexpr size_t OFF_GP = OFF_ZH + 33554432;               // partial G tiles
constexpr size_t GP_LEN = (size_t)3 * NB * NCHUNK * 128 * 128;  // 12.58M floats
constexpr size_t WS_NEED_NEW = (OFF_ZH + 33554432) * sizeof(float);  // ~145.2 MB
constexpr size_t WS_NEED_V3  = (OFF_GP + GP_LEN) * sizeof(float);    // ~195.6 MB

// =================================================================
// NEW PATH (f16 MFMA)
// =================================================================

// Convert: Z = [y; x] per batch -> f16, plus row sums S (atomic).
__global__ __launch_bounds__(256) void convert_kernel(
    const float* __restrict__ x, const float* __restrict__ y,
    _Float16* __restrict__ Zh, float* __restrict__ S)
{
  const int seg = blockIdx.x;          // 0..7 (4096 elements each)
  const int r   = blockIdx.y;          // 0..255
  const int b   = blockIdx.z;
  const float* src = ((r < CH) ? (y + ((size_t)b*CH + r)*NPTS)
                               : (x + ((size_t)b*CH + (r-CH))*NPTS)) + (size_t)seg*4096;
  _Float16* dst = Zh + ((size_t)b*TWOC + r)*NPTS + (size_t)seg*4096;
  const int tid = threadIdx.x;

  float s = 0.f;
  const float4* s4 = (const float4*)(src + tid*16);
  union { uint4 u; _Float16 h[8]; } p0, p1;
  float4 a = s4[0], bq = s4[1], c = s4[2], d = s4[3];
  p0.h[0]=(_Float16)a.x;  p0.h[1]=(_Float16)a.y;  p0.h[2]=(_Float16)a.z;  p0.h[3]=(_Float16)a.w;
  p0.h[4]=(_Float16)bq.x; p0.h[5]=(_Float16)bq.y; p0.h[6]=(_Float16)bq.z; p0.h[7]=(_Float16)bq.w;
  p1.h[0]=(_Float16)c.x;  p1.h[1]=(_Float16)c.y;  p1.h[2]=(_Float16)c.z;  p1.h[3]=(_Float16)c.w;
  p1.h[4]=(_Float16)d.x;  p1.h[5]=(_Float16)d.y;  p1.h[6]=(_Float16)d.z;  p1.h[7]=(_Float16)d.w;
  s += a.x+a.y+a.z+a.w + bq.x+bq.y+bq.z+bq.w + c.x+c.y+c.z+c.w + d.x+d.y+d.z+d.w;
  *(uint4*)(dst + tid*16)     = p0.u;
  *(uint4*)(dst + tid*16 + 8) = p1.u;

  for (int off = 32; off > 0; off >>= 1) s += __shfl_down(s, off);
  if ((tid & 63) == 0) atomicAdd(&S[b*TWOC + r], s);
}

// -----------------------------------------------------------------
// gram_mfma3: Gram via MFMA f16, global_load_lds staging (pre-swizzled
// source, linear LDS dest), double-buffered with counted vmcnt, partial
// stores to GP (no atomics) + XCD-grouped tile siblings for L2 reuse.
// Grid: 768 blocks x 256 threads.  LDS: 128 KB (fits 160 KB/CU, 1 blk/CU).
// -----------------------------------------------------------------
__global__ __launch_bounds__(256) void gram_mfma3(
    const _Float16* __restrict__ Zh, float* __restrict__ G, float* __restrict__ GP)
{
  __shared__ __align__(16) _Float16 As[2][128 * KSTAGE];
  __shared__ __align__(16) _Float16 Bs[2][128 * KSTAGE];

  // XCD-grouped mapping: hw%8 = XCD (round-robin dispatch). The 3 tile
  // siblings (t=0,1,2) of one (kc,b) group are consecutive on one XCD so
  // the two 256KB Zh half-chunks are fetched once into that XCD's L2.
  const int hw    = blockIdx.x;        // 0..767
  const int xcd   = hw & 7;
  const int local = hw >> 3;           // 0..95
  const int t     = local % 3;         // tile: 0:(0,0) 1:(128,0) 2:(128,128)
  const int grp   = local / 3;         // 0..31
  const int gidx  = xcd * 32 + grp;    // 0..255
  const int kc    = gidx & 31;
  const int b     = gidx >> 5;

  const int i0 = (t == 0) ? 0 : CH;
  const int j0 = (t == 2) ? CH : 0;
  const _Float16* Ar = Zh + ((size_t)b*TWOC + i0)*NPTS + (size_t)kc*KC3;
  const _Float16* Br = Zh + ((size_t)b*TWOC + j0)*NPTS + (size_t)kc*KC3;

  const int tid   = threadIdx.x;
  const int lane  = tid & 63;
  const int wave  = tid >> 6;
  const int mbase = (wave & 1) * 64;
  const int nbase = (wave >> 1) * 64;
  const int m0    = lane & 15;
  const int quad  = lane >> 4;

  // Staging map: linear 16B granule slot s = wave*512 + i*64 + lane
  //   row = s>>4 (16 granules of 16B per row = 256B), g = s&15.
  // LDS dest is linear (wave-uniform base + lane*16); the swizzle lives in
  // the per-lane GLOBAL source granule gs = g ^ (row&7)  [rule 21].
  const int srow = (wave * 512) >> 4;  // base row of this wave's slots

#define STAGE(buf, k0)                                                        \
  {                                                                           \
    _Pragma("unroll")                                                         \
    for (int i = 0; i < 8; i++) {                                             \
      const int s = wave*512 + i*64 + lane;                                   \
      const int r = s >> 4;                                                   \
      const int g = s & 15;                                                   \
      const int gs = g ^ (r & 7);                                             \
      __builtin_amdgcn_global_load_lds(                                       \
        (const __attribute__((address_space(1))) void*)(Ar + (size_t)r*NPTS + (k0) + gs*8), \
        (__attribute__((address_space(3))) void*)&As[buf][(wave*512 + i*64)*8], \
        16, 0, 0);                                                            \
      __builtin_amdgcn_global_load_lds(                                       \
        (const __attribute__((address_space(1))) void*)(Br + (size_t)r*NPTS + (k0) + gs*8), \
        (__attribute__((address_space(3))) void*)&Bs[buf][(wave*512 + i*64)*8], \
        16, 0, 0);                                                            \
    }                                                                         \
  }

  floatx4 acc[4][4];
  #pragma unroll
  for (int i = 0; i < 4; i++)
    #pragma unroll
    for (int j = 0; j < 4; j++) acc[i][j] = (floatx4){0.f,0.f,0.f,0.f};

  (void)srow;
  STAGE(0, 0);                         // 16 loads in flight per thread

  int cur = 0;
  for (int st = 0; st < NST; ++st) {
    if (st + 1 < NST) {
      STAGE(cur ^ 1, (st + 1) * KSTAGE);               // +16 -> 32 in flight
      asm volatile("s_waitcnt vmcnt(16)" ::: "memory"); // stage st landed; st+1 flies on
    } else {
      asm volatile("s_waitcnt vmcnt(0)" ::: "memory");
    }
    __builtin_amdgcn_s_barrier();

    #pragma unroll
    for (int kk = 0; kk < 4; kk++) {
      half8 af[4], bf[4];
      #pragma unroll
      for (int i = 0; i < 4; i++) {
        const int ra = mbase + i*16 + m0;
        const int ga = (kk*4 + quad) ^ (ra & 7);
        af[i] = *(const half8*)&As[cur][ra*KSTAGE + ga*8];
        const int rb = nbase + i*16 + m0;
        const int gb = (kk*4 + quad) ^ (rb & 7);
        bf[i] = *(const half8*)&Bs[cur][rb*KSTAGE + gb*8];
      }
      #pragma unroll
      for (int i = 0; i < 4; i++)
        #pragma unroll
        for (int j = 0; j < 4; j++)
          acc[i][j] = __builtin_amdgcn_mfma_f32_16x16x32_f16(af[i], bf[j], acc[i][j], 0, 0, 0);
    }

    __builtin_amdgcn_s_barrier();      // readers done before next STAGE overwrites
    cur ^= 1;
  }
#undef STAGE

  // Epilogue: C/D layout col=lane&15, row=quad*4+reg (verified m89/m91)
  if (GP != nullptr) {
    // partial store, no atomics; reduced by greduce_kernel
    float* gp = GP + (((size_t)(b*3 + t)*NCHUNK + kc) * (128*128));
    #pragma unroll
    for (int i = 0; i < 4; i++)
      #pragma unroll
      for (int j = 0; j < 4; j++)
        #pragma unroll
        for (int rg = 0; rg < 4; rg++) {
          const int row = mbase + i*16 + quad*4 + rg;
          const int col = nbase + j*16 + m0;
          gp[row*128 + col] = acc[i][j][rg];
        }
  } else {
    #pragma unroll
    for (int i = 0; i < 4; i++)
      #pragma unroll
      for (int j = 0; j < 4; j++)
        #pragma unroll
        for (int rg = 0; rg < 4; rg++) {
          const int row = i0 + mbase + i*16 + quad*4 + rg;
          const int col = j0 + nbase + j*16 + m0;
          atomicAdd(&G[((size_t)b*TWOC + row)*TWOC + col], acc[i][j][rg]);
        }
  }
}

// Reduce the 32 K-chunk partials into G's three unique quadrants.
// grid (64, 3, 8) x 256 thr; coalesced strided reads.
__global__ __launch_bounds__(256) void greduce_kernel(
    const float* __restrict__ GP, float* __restrict__ G)
{
  const int t   = blockIdx.y;
  const int b   = blockIdx.z;
  const int idx = blockIdx.x * 256 + threadIdx.x;   // 0..16383
  const float* gp = GP + ((size_t)(b*3 + t)*NCHUNK) * (128*128) + idx;
  float s = 0.f;
  #pragma unroll
  for (int k = 0; k < NCHUNK; k++) s += gp[(size_t)k * (128*128)];
  const int i0 = (t == 0) ? 0 : CH;
  const int j0 = (t == 2) ? CH : 0;
  const int row = idx >> 7, col = idx & 127;
  G[((size_t)b*TWOC + i0 + row)*TWOC + j0 + col] = s;
}

// out = M(128x256,f16) @ Z(256xN,f16) + C0 via MFMA.
__global__ __launch_bounds__(256) void out_mfma(
    const _Float16* __restrict__ Zh, const _Float16* __restrict__ Mh,
    const float* __restrict__ C0, float* __restrict__ out)
{
  const int n0 = blockIdx.x * 128;
  const int b  = blockIdx.y;

  __shared__ __align__(16) _Float16 As[128*64];   // M slice [c][d], swizzled
  __shared__ __align__(16) _Float16 Bs[128*72];   // Z^T slice [n][d], pad stride 72

  const int tid   = threadIdx.x;
  const int lane  = tid & 63;
  const int wave  = tid >> 6;
  const int mbase = (wave & 1) * 64;   // c
  const int nbase = (wave >> 1) * 64;  // n
  const int m0    = lane & 15;
  const int quad  = lane >> 4;

  const int srow  = tid >> 1;
  const int gbase = (tid & 1) * 4;
  const int dl    = tid >> 4;          // 0..15
  const int ng    = tid & 15;          // 0..15

  floatx4 acc[4][4];
  #pragma unroll
  for (int i = 0; i < 4; i++)
    #pragma unroll
    for (int j = 0; j < 4; j++) acc[i][j] = (floatx4){0.f,0.f,0.f,0.f};

  for (int d0 = 0; d0 < TWOC; d0 += 64) {
    __syncthreads();
    #pragma unroll
    for (int q = 0; q < 4; q++) {
      const int g  = gbase + q;
      const int gp = g ^ (srow & 7);
      *(uint4*)&As[(size_t)(srow*8 + gp)*8] =
          *(const uint4*)(Mh + ((size_t)b*CH + srow)*TWOC + d0 + g*8);
    }
    #pragma unroll
    for (int ds = 0; ds < 4; ds++) {
      const int d = dl + ds*16;
      union { uint4 u; _Float16 h[8]; } v;
      v.u = *(const uint4*)(Zh + ((size_t)b*TWOC + d0 + d)*NPTS + n0 + ng*8);
      #pragma unroll
      for (int e = 0; e < 8; e++)
        Bs[(size_t)(ng*8 + e)*72 + d] = v.h[e];
    }
    __syncthreads();
    #pragma unroll
    for (int ks = 0; ks < 2; ks++) {
      half8 af[4], bf[4];
      #pragma unroll
      for (int i = 0; i < 4; i++) {
        const int ra = mbase + i*16 + m0;
        const int ga = (ks*4 + quad) ^ (ra & 7);
        af[i] = *(const half8*)&As[(size_t)(ra*8 + ga)*8];
        const int rn = nbase + i*16 + m0;
        bf[i] = *(const half8*)&Bs[(size_t)rn*72 + ks*32 + quad*8];
      }
      #pragma unroll
      for (int i = 0; i < 4; i++)
        #pragma unroll
        for (int j = 0; j < 4; j++)
          acc[i][j] = __builtin_amdgcn_mfma_f32_16x16x32_f16(af[i], bf[j], acc[i][j], 0, 0, 0);
    }
  }

  #pragma unroll
  for (int i = 0; i < 4; i++) {
    #pragma unroll
    for (int rg = 0; rg < 4; rg++) {
      const int c  = mbase + i*16 + quad*4 + rg;
      const float cv = C0[b*CH + c];
      #pragma unroll
      for (int j = 0; j < 4; j++) {
        const int n = n0 + nbase + j*16 + m0;
        out[((size_t)b*CH + c)*NPTS + n] = acc[i][j][rg] + cv;
      }
    }
  }
}

// mout variant writing f16 M
__global__ void mout_f16_kernel(const float* __restrict__ ATT, const float* __restrict__ v1w,
                                const float* __restrict__ v2w, const float* __restrict__ v1b,
                                const float* __restrict__ v2b, _Float16* __restrict__ Mh,
                                float* __restrict__ C0)
{
  const int c = blockIdx.x, b = blockIdx.y, j = threadIdx.x;  // j: 0..255
  __shared__ float acol[TWOC];
  acol[j] = ATT[((size_t)b*TWOC + j)*CH + c];
  __syncthreads();
  float acc = 0.f;
  if (j < CH) {
    for (int d = 0; d < CH; d++) acc = fmaf(acol[d], v2w[(size_t)d*CH + j], acc);
  } else {
    const int jj = j - CH;
    for (int d = 0; d < CH; d++) acc = fmaf(acol[CH + d], v1w[(size_t)d*CH + jj], acc);
  }
  Mh[((size_t)b*CH + c)*TWOC + j] = (_Float16)acc;
  if (j == 0) {
    float s = 0.f;
    for (int d = 0; d < CH; d++) s += acol[d]*v2b[d] + acol[CH+d]*v1b[d];
    C0[b*CH + c] = s;
  }
}

// =================================================================
// SHARED small-chain kernels (both paths)
// =================================================================
__global__ void pmirror_kernel(const float* __restrict__ S, const float* __restrict__ qw,
                               const float* __restrict__ kw, float* __restrict__ P,
                               float* __restrict__ G)
{
  const int b = blockIdx.x;
  const int tid = threadIdx.x;
  const float* w = (tid < CH) ? (qw + (size_t)tid*CH) : (kw + (size_t)(tid-CH)*CH);
  const float* s = S + b*TWOC + ((tid < CH) ? 0 : CH);
  float acc = 0.f;
  for (int j = 0; j < CH; j++) acc = fmaf(w[j], s[j], acc);
  P[b*TWOC + tid] = acc;

  float* Gb = G + (size_t)b * TWOC * TWOC;
  for (int idx = tid; idx < CH*CH; idx += 256) {
    const int i2 = idx >> 7, j2 = idx & 127;
    Gb[(size_t)i2*TWOC + CH + j2] = Gb[(size_t)(CH + j2)*TWOC + i2];
  }
}

__global__ void h_kernel(const float* __restrict__ G, const float* __restrict__ qw,
                         const float* __restrict__ kw, float* __restrict__ H)
{
  const int i = blockIdx.x, b = blockIdx.y, k = threadIdx.x;
  const float* w = (i < CH) ? (qw + (size_t)i*CH) : (kw + (size_t)(i-CH)*CH);
  const int jbase = (i < CH) ? 0 : CH;
  const float* g = G + ((size_t)b*TWOC + jbase)*TWOC + k;
  float acc = 0.f;
  for (int j = 0; j < CH; j++) acc = fmaf(w[j], g[(size_t)j*TWOC], acc);
  H[((size_t)b*TWOC + i)*TWOC + k] = acc;
}

__global__ void e_kernel(const float* __restrict__ H, const float* __restrict__ qw,
                         const float* __restrict__ kw, const float* __restrict__ qb,
                         const float* __restrict__ kb, const float* __restrict__ P,
                         float* __restrict__ E)
{
  const int i = blockIdx.x, b = blockIdx.y, j = threadIdx.x;
  const float* h = H + ((size_t)b*TWOC + i)*TWOC + ((j < CH) ? 0 : CH);
  const float* w = (j < CH) ? (qw + (size_t)j*CH) : (kw + (size_t)(j-CH)*CH);
  const float bcj = (j < CH) ? qb[j] : kb[j-CH];
  const float bci = (i < CH) ? qb[i] : kb[i-CH];
  const float4* h4 = (const float4*)h;
  const float4* w4 = (const float4*)w;
  float acc = 0.f;
  for (int k = 0; k < CH/4; k++) {
    const float4 hv = h4[k], wv = w4[k];
    acc += hv.x*wv.x + hv.y*wv.y + hv.z*wv.z + hv.w*wv.w;
  }
  acc += P[b*TWOC+i]*bcj + bci*P[b*TWOC+j] + (float)NPTS * bci * bcj;
  E[((size_t)b*TWOC + i)*TWOC + j] = acc * (1.0f/16.0f);
}

__global__ void t1_kernel(const float* __restrict__ E, const float* __restrict__ t1w,
                          const float* __restrict__ t1b, float* __restrict__ E1)
{
  const int i = blockIdx.x, b = blockIdx.y, j = threadIdx.x;
  const float4* e4 = (const float4*)(E + ((size_t)b*TWOC + i)*TWOC);
  const float4* w4 = (const float4*)(t1w + (size_t)j*TWOC);
  float acc = t1b[j];
  for (int k = 0; k < TWOC/4; k++) {
    const float4 ev = e4[k], wv = w4[k];
    acc += ev.x*wv.x + ev.y*wv.y + ev.z*wv.z + ev.w*wv.w;
  }
  E1[((size_t)b*TWOC + i)*TWOC + j] = fmaxf(acc, 0.f);
}

__global__ void t2_kernel(const float* __restrict__ E1, const float* __restrict__ t2w,
                          const float* __restrict__ t2b, float* __restrict__ E2)
{
  const int i = blockIdx.x, b = blockIdx.y, j = threadIdx.x;
  const float4* e4 = (const float4*)(E1 + ((size_t)b*TWOC + i)*TWOC);
  const float4* w4 = (const float4*)(t2w + (size_t)j*TWOC);
  float acc = t2b[j];
  for (int k = 0; k < TWOC/4; k++) {
    const float4 ev = e4[k], wv = w4[k];
    acc += ev.x*wv.x + ev.y*wv.y + ev.z*wv.z + ev.w*wv.w;
  }
  E2[((size_t)b*TWOC + i)*CH + j] = fmaxf(acc, 0.f);
}

__global__ void softmax_kernel(const float* __restrict__ E2, float* __restrict__ ATT)
{
  const int b = blockIdx.x;
  const int i = threadIdx.x;
  const float* r = E2  + ((size_t)b*TWOC + i)*CH;
  float*       o = ATT + ((size_t)b*TWOC + i)*CH;
  float m = -1e30f;
  for (int j = 0; j < CH; j++) m = fmaxf(m, r[j]);
  float s = 0.f;
  for (int j = 0; j < CH; j++) s += expf(r[j] - m);
  const float inv = 1.f / s;
  for (int j = 0; j < CH; j++) o[j] = expf(r[j] - m) * inv;
}

// =================================================================
// FALLBACK PATH (R1 fp32 kernels, used only if ws too small)
// =================================================================
__global__ __launch_bounds__(256) void gram_kernel(
    const float* __restrict__ x, const float* __restrict__ y,
    float* __restrict__ G, float* __restrict__ S)
{
  const int t  = blockIdx.x;
  const int kc = blockIdx.y;
  const int b  = blockIdx.z;
  const float* Ab = (t == 0) ? y : x;
  const float* Bb = (t == 2) ? x : y;
  const int growA = (t == 0) ? 0 : CH;
  const int gcolB = (t == 2) ? CH : 0;
  const float* Ap = Ab + (size_t)b * CH * NPTS + (size_t)kc * KC;
  const float* Bp = Bb + (size_t)b * CH * NPTS + (size_t)kc * KC;

  __shared__ __align__(16) float As[8][128];
  __shared__ __align__(16) float Bs[8][128];

  const int tid  = threadIdx.x;
  const int ti   = tid >> 4;
  const int tj   = tid & 15;
  const int lrow = tid >> 1;
  const int lk4  = (tid & 1) * 4;

  const float* arow = Ap + (size_t)lrow * NPTS + lk4;
  const float* brow = Bp + (size_t)lrow * NPTS + lk4;

  float acc[8][8];
  #pragma unroll
  for (int i = 0; i < 8; i++)
    #pragma unroll
    for (int j = 0; j < 8; j++) acc[i][j] = 0.f;
  float asum = 0.f;

  for (int k0 = 0; k0 < KC; k0 += 8) {
    const float4 av = *(const float4*)(arow + k0);
    const float4 bv = *(const float4*)(brow + k0);
    __syncthreads();
    As[lk4+0][lrow] = av.x; As[lk4+1][lrow] = av.y;
    As[lk4+2][lrow] = av.z; As[lk4+3][lrow] = av.w;
    Bs[lk4+0][lrow] = bv.x; Bs[lk4+1][lrow] = bv.y;
    Bs[lk4+2][lrow] = bv.z; Bs[lk4+3][lrow] = bv.w;
    asum += av.x + av.y + av.z + av.w;
    __syncthreads();
    #pragma unroll
    for (int kk = 0; kk < 8; kk++) {
      float a[8], bb[8];
      *(float4*)&a[0]  = *(const float4*)&As[kk][ti*8];
      *(float4*)&a[4]  = *(const float4*)&As[kk][ti*8+4];
      *(float4*)&bb[0] = *(const float4*)&Bs[kk][tj*8];
      *(float4*)&bb[4] = *(const float4*)&Bs[kk][tj*8+4];
      #pragma unroll
      for (int ii = 0; ii < 8; ii++)
        #pragma unroll
        for (int jj = 0; jj < 8; jj++)
          acc[ii][jj] = fmaf(a[ii], bb[jj], acc[ii][jj]);
    }
  }

  float* Gp = G + ((size_t)b * TWOC + growA) * TWOC + gcolB;
  #pragma unroll
  for (int ii = 0; ii < 8; ii++)
    #pragma unroll
    for (int jj = 0; jj < 8; jj++)
      atomicAdd(&Gp[(size_t)(ti*8+ii) * TWOC + (tj*8+jj)], acc[ii][jj]);

  if (t == 0)      atomicAdd(&S[b*TWOC + lrow],      asum);
  else if (t == 2) atomicAdd(&S[b*TWOC + CH + lrow], asum);
}

__global__ void mout_f32_kernel(const float* __restrict__ ATT, const float* __restrict__ v1w,
                                const float* __restrict__ v2w, const float* __restrict__ v1b,
                                const float* __restrict__ v2b, float* __restrict__ M,
                                float* __restrict__ C0)
{
  const int c = blockIdx.x, b = blockIdx.y, j = threadIdx.x;
  __shared__ float acol[TWOC];
  acol[j] = ATT[((size_t)b*TWOC + j)*CH + c];
  __syncthreads();
  float acc = 0.f;
  if (j < CH) {
    for (int d = 0; d < CH; d++) acc = fmaf(acol[d], v2w[(size_t)d*CH + j], acc);
  } else {
    const int jj = j - CH;
    for (int d = 0; d < CH; d++) acc = fmaf(acol[CH + d], v1w[(size_t)d*CH + jj], acc);
  }
  M[((size_t)b*CH + c)*TWOC + j] = acc;
  if (j == 0) {
    float s = 0.f;
    for (int d = 0; d < CH; d++) s += acol[d]*v2b[d] + acol[CH+d]*v1b[d];
    C0[b*CH + c] = s;
  }
}

__global__ __launch_bounds__(256) void out_kernel(
    const float* __restrict__ x, const float* __restrict__ y,
    const float* __restrict__ M, const float* __restrict__ C0,
    float* __restrict__ out)
{
  const int b  = blockIdx.y;
  const int n0 = blockIdx.x * 64;
  const int tid = threadIdx.x;
  const int tc = tid & 15;
  const int tn = tid >> 4;

  __shared__ __align__(16) float Ms[64][128];
  __shared__ __align__(16) float Zs[64][64];

  float acc[8][4];
  #pragma unroll
  for (int i = 0; i < 8; i++)
    #pragma unroll
    for (int j = 0; j < 4; j++) acc[i][j] = 0.f;

  const float* Mb = M + (size_t)b * CH * TWOC;

  for (int chunk = 0; chunk < 4; chunk++) {
    const int kbase = chunk * 64;
    const float* Zsrc = ((chunk < 2) ? y : x) + (size_t)b * CH * NPTS
                        + (size_t)((chunk & 1) * 64) * NPTS;
    __syncthreads();
    {
      const int c   = tid >> 1;
      const int kb2 = (tid & 1) * 32;
      const float* mr = Mb + (size_t)c * TWOC + kbase + kb2;
      #pragma unroll
      for (int q = 0; q < 8; q++) {
        const float4 v = *(const float4*)(mr + q*4);
        Ms[kb2 + q*4 + 0][c] = v.x;
        Ms[kb2 + q*4 + 1][c] = v.y;
        Ms[kb2 + q*4 + 2][c] = v.z;
        Ms[kb2 + q*4 + 3][c] = v.w;
      }
      const int kk  = tid >> 2;
      const int nb4 = (tid & 3) * 4;
      const float* zr = Zsrc + (size_t)kk * NPTS + n0 + nb4;
      #pragma unroll
      for (int q = 0; q < 4; q++)
        *(float4*)&Zs[kk][nb4 + q*16] = *(const float4*)(zr + q*16);
    }
    __syncthreads();
    #pragma unroll 8
    for (int kk = 0; kk < 64; kk++) {
      float a[8], zz[4];
      *(float4*)&a[0]  = *(const float4*)&Ms[kk][tc*8];
      *(float4*)&a[4]  = *(const float4*)&Ms[kk][tc*8+4];
      *(float4*)&zz[0] = *(const float4*)&Zs[kk][tn*4];
      #pragma unroll
      for (int ii = 0; ii < 8; ii++)
        #pragma unroll
        for (int jj = 0; jj < 4; jj++)
          acc[ii][jj] = fmaf(a[ii], zz[jj], acc[ii][jj]);
    }
  }

  #pragma unroll
  for (int ii = 0; ii < 8; ii++) {
    const int c = tc*8 + ii;
    const float cv = C0[b*CH + c];
    float4 o;
    o.x = acc[ii][0] + cv; o.y = acc[ii][1] + cv;
    o.z = acc[ii][2] + cv; o.w = acc[ii][3] + cv;
    *(float4*)&out[((size_t)b*CH + c)*NPTS + n0 + tn*4] = o;
  }
}

// -----------------------------------------------------------------
extern "C" void kernel_launch(void* const* d_in, const int* in_sizes, int n_in,
                              void* d_out, int out_size, void* d_ws, size_t ws_size,
                              hipStream_t stream)
{
  const float* x   = (const float*)d_in[0];
  const float* y   = (const float*)d_in[1];
  const float* qw  = (const float*)d_in[2];
  const float* qb  = (const float*)d_in[3];
  const float* kw  = (const float*)d_in[4];
  const float* kb  = (const float*)d_in[5];
  const float* v1w = (const float*)d_in[6];
  const float* v1b = (const float*)d_in[7];
  const float* v2w = (const float*)d_in[8];
  const float* v2b = (const float*)d_in[9];
  const float* t1w = (const float*)d_in[10];
  const float* t1b = (const float*)d_in[11];
  const float* t2w = (const float*)d_in[12];
  const float* t2b = (const float*)d_in[13];

  float* ws = (float*)d_ws;
  float* G  = ws + OFF_G;
  float* S  = ws + OFF_S;
  float* P  = ws + OFF_P;
  float* H  = ws + OFF_H;
  float* E  = ws + OFF_E;
  float* E1 = ws + OFF_E1;
  float* E2 = ws + OFF_E2;
  float* AT = ws + OFF_AT;
  float* C0 = ws + OFF_C0;
  float* outp = (float*)d_out;

  // zero G and S
  hipMemsetAsync(d_ws, 0, (OFF_S + 2048) * sizeof(float), stream);

  if (ws_size >= WS_NEED_NEW) {
    _Float16* Mh = (_Float16*)(ws + OFF_MH);
    _Float16* Zh = (_Float16*)(ws + OFF_ZH);
    const bool useGP = (ws_size >= WS_NEED_V3);
    float* GP = useGP ? (ws + OFF_GP) : nullptr;

    convert_kernel<<<dim3(NPTS/4096, TWOC, NB), 256, 0, stream>>>(x, y, Zh, S);
    gram_mfma3    <<<dim3(3 * NCHUNK * NB),     256, 0, stream>>>(Zh, G, GP);
    if (useGP)
      greduce_kernel<<<dim3(64, 3, NB),         256, 0, stream>>>(GP, G);
    pmirror_kernel<<<dim3(NB),                  256, 0, stream>>>(S, qw, kw, P, G);
    h_kernel      <<<dim3(TWOC, NB),            256, 0, stream>>>(G, qw, kw, H);
    e_kernel      <<<dim3(TWOC, NB),            256, 0, stream>>>(H, qw, kw, qb, kb, P, E);
    t1_kernel     <<<dim3(TWOC, NB),            256, 0, stream>>>(E, t1w, t1b, E1);
    t2_kernel     <<<dim3(TWOC, NB),            128, 0, stream>>>(E1, t2w, t2b, E2);
    softmax_kernel<<<dim3(NB),                  256, 0, stream>>>(E2, AT);
    mout_f16_kernel<<<dim3(CH, NB),             256, 0, stream>>>(AT, v1w, v2w, v1b, v2b, Mh, C0);
    out_mfma      <<<dim3(NPTS/128, NB),        256, 0, stream>>>(Zh, Mh, C0, outp);
  } else {
    float* Mo = ws + OFF_MH;
    gram_kernel   <<<dim3(3, NPTS/KC, NB), 256, 0, stream>>>(x, y, G, S);
    pmirror_kernel<<<dim3(NB),             256, 0, stream>>>(S, qw, kw, P, G);
    h_kernel      <<<dim3(TWOC, NB),       256, 0, stream>>>(G, qw, kw, H);
    e_kernel      <<<dim3(TWOC, NB),       256, 0, stream>>>(H, qw, kw, qb, kb, P, E);
    t1_kernel     <<<dim3(TWOC, NB),       256, 0, stream>>>(E, t1w, t1b, E1);
    t2_kernel     <<<dim3(TWOC, NB),       128, 0, stream>>>(E1, t2w, t2b, E2);
    softmax_kernel<<<dim3(NB),             256, 0, stream>>>(E2, AT);
    mout_f32_kernel<<<dim3(CH, NB),        256, 0, stream>>>(AT, v1w, v2w, v1b, v2b, Mo, C0);
    out_kernel    <<<dim3(NPTS/64, NB),    256, 0, stream>>>(x, y, Mo, C0, outp);
  }
}

// Round 2
// 615.527 us; speedup vs baseline: 1.2976x; 1.1358x over previous
//
#include <hip/hip_runtime.h>

// Problem constants
constexpr int CH   = 128;    // C
constexpr int TWOC = 256;    // 2C
constexpr int NPTS = 32768;  // N
constexpr int NB   = 8;      // B
constexpr int KC   = 2048;   // K-chunk for fallback fp32 gram

// gram_mfma3 geometry
constexpr int KC3    = 1024; // K per block (32 chunks)
constexpr int KSTAGE = 128;  // K per LDS stage (256B per row burst)
constexpr int NST    = KC3 / KSTAGE;  // 8 stages
constexpr int NCHUNK = NPTS / KC3;    // 32

typedef _Float16 half8 __attribute__((ext_vector_type(8)));
typedef float floatx4 __attribute__((ext_vector_type(4)));

// ---------------- Workspace layout (float offsets) ----------------
constexpr size_t OFF_G  = 0;
constexpr size_t OFF_S  = 524288;
constexpr size_t OFF_P  = 526336;
constexpr size_t OFF_H  = 528384;
constexpr size_t OFF_E  = 1052672;
constexpr size_t OFF_E1 = 1576960;
constexpr size_t OFF_E2 = 2101248;
constexpr size_t OFF_AT = 2363392;
constexpr size_t OFF_C0 = 2625536;
constexpr size_t OFF_MH = 2626560;
constexpr size_t OFF_ZH = 2757632;
constexpr size_t OFF_GP = OFF_ZH + 33554432;               // partial G tiles
constexpr size_t GP_LEN = (size_t)3 * NB * NCHUNK * 128 * 128;  // 12.58M floats
constexpr size_t WS_NEED_NEW = (OFF_ZH + 33554432) * sizeof(float);  // ~145.2 MB
constexpr size_t WS_NEED_V3  = (OFF_GP + GP_LEN) * sizeof(float);    // ~195.6 MB

// =================================================================
// NEW PATH (f16 MFMA)
// =================================================================

// Convert: Z = [y; x] per batch -> f16, plus row sums S (atomic).
// Lane-contiguous float4 reads (1KB/wave/inst) + uint2 f16 writes.
__global__ __launch_bounds__(256) void convert_kernel(
    const float* __restrict__ x, const float* __restrict__ y,
    _Float16* __restrict__ Zh, float* __restrict__ S)
{
  const int seg = blockIdx.x;          // 0..7 (4096 elements each)
  const int r   = blockIdx.y;          // 0..255
  const int b   = blockIdx.z;
  const float* src = ((r < CH) ? (y + ((size_t)b*CH + r)*NPTS)
                               : (x + ((size_t)b*CH + (r-CH))*NPTS)) + (size_t)seg*4096;
  _Float16* dst = Zh + ((size_t)b*TWOC + r)*NPTS + (size_t)seg*4096;
  const int tid = threadIdx.x;

  float s = 0.f;
  #pragma unroll
  for (int it = 0; it < 4; it++) {
    const int idx = it*1024 + tid*4;
    const float4 v = *(const float4*)(src + idx);
    union { uint2 u; _Float16 h[4]; } p;
    p.h[0]=(_Float16)v.x; p.h[1]=(_Float16)v.y; p.h[2]=(_Float16)v.z; p.h[3]=(_Float16)v.w;
    *(uint2*)(dst + idx) = p.u;
    s += v.x + v.y + v.z + v.w;
  }

  for (int off = 32; off > 0; off >>= 1) s += __shfl_down(s, off);
  if ((tid & 63) == 0) atomicAdd(&S[b*TWOC + r], s);
}

// -----------------------------------------------------------------
// gram_mfma3: Gram via MFMA f16, global_load_lds staging (pre-swizzled
// source, linear LDS dest), double-buffered with counted vmcnt, partial
// stores to GP (no atomics) + XCD-grouped tile siblings for L2 reuse.
// -----------------------------------------------------------------
__global__ __launch_bounds__(256) void gram_mfma3(
    const _Float16* __restrict__ Zh, float* __restrict__ G, float* __restrict__ GP)
{
  __shared__ __align__(16) _Float16 As[2][128 * KSTAGE];
  __shared__ __align__(16) _Float16 Bs[2][128 * KSTAGE];

  const int hw    = blockIdx.x;        // 0..767
  const int xcd   = hw & 7;
  const int local = hw >> 3;           // 0..95
  const int t     = local % 3;         // tile: 0:(0,0) 1:(128,0) 2:(128,128)
  const int grp   = local / 3;         // 0..31
  const int gidx  = xcd * 32 + grp;    // 0..255
  const int kc    = gidx & 31;
  const int b     = gidx >> 5;

  const int i0 = (t == 0) ? 0 : CH;
  const int j0 = (t == 2) ? CH : 0;
  const _Float16* Ar = Zh + ((size_t)b*TWOC + i0)*NPTS + (size_t)kc*KC3;
  const _Float16* Br = Zh + ((size_t)b*TWOC + j0)*NPTS + (size_t)kc*KC3;

  const int tid   = threadIdx.x;
  const int lane  = tid & 63;
  const int wave  = tid >> 6;
  const int mbase = (wave & 1) * 64;
  const int nbase = (wave >> 1) * 64;
  const int m0    = lane & 15;
  const int quad  = lane >> 4;

#define STAGE(buf, k0)                                                        \
  {                                                                           \
    _Pragma("unroll")                                                         \
    for (int i = 0; i < 8; i++) {                                             \
      const int s = wave*512 + i*64 + lane;                                   \
      const int r = s >> 4;                                                   \
      const int g = s & 15;                                                   \
      const int gs = g ^ (r & 7);                                             \
      __builtin_amdgcn_global_load_lds(                                       \
        (const __attribute__((address_space(1))) void*)(Ar + (size_t)r*NPTS + (k0) + gs*8), \
        (__attribute__((address_space(3))) void*)&As[buf][(wave*512 + i*64)*8], \
        16, 0, 0);                                                            \
      __builtin_amdgcn_global_load_lds(                                       \
        (const __attribute__((address_space(1))) void*)(Br + (size_t)r*NPTS + (k0) + gs*8), \
        (__attribute__((address_space(3))) void*)&Bs[buf][(wave*512 + i*64)*8], \
        16, 0, 0);                                                            \
    }                                                                         \
  }

  floatx4 acc[4][4];
  #pragma unroll
  for (int i = 0; i < 4; i++)
    #pragma unroll
    for (int j = 0; j < 4; j++) acc[i][j] = (floatx4){0.f,0.f,0.f,0.f};

  STAGE(0, 0);

  int cur = 0;
  for (int st = 0; st < NST; ++st) {
    if (st + 1 < NST) {
      STAGE(cur ^ 1, (st + 1) * KSTAGE);
      asm volatile("s_waitcnt vmcnt(16)" ::: "memory");
    } else {
      asm volatile("s_waitcnt vmcnt(0)" ::: "memory");
    }
    __builtin_amdgcn_s_barrier();

    #pragma unroll
    for (int kk = 0; kk < 4; kk++) {
      half8 af[4], bf[4];
      #pragma unroll
      for (int i = 0; i < 4; i++) {
        const int ra = mbase + i*16 + m0;
        const int ga = (kk*4 + quad) ^ (ra & 7);
        af[i] = *(const half8*)&As[cur][ra*KSTAGE + ga*8];
        const int rb = nbase + i*16 + m0;
        const int gb = (kk*4 + quad) ^ (rb & 7);
        bf[i] = *(const half8*)&Bs[cur][rb*KSTAGE + gb*8];
      }
      #pragma unroll
      for (int i = 0; i < 4; i++)
        #pragma unroll
        for (int j = 0; j < 4; j++)
          acc[i][j] = __builtin_amdgcn_mfma_f32_16x16x32_f16(af[i], bf[j], acc[i][j], 0, 0, 0);
    }

    __builtin_amdgcn_s_barrier();
    cur ^= 1;
  }
#undef STAGE

  if (GP != nullptr) {
    float* gp = GP + (((size_t)(b*3 + t)*NCHUNK + kc) * (128*128));
    #pragma unroll
    for (int i = 0; i < 4; i++)
      #pragma unroll
      for (int j = 0; j < 4; j++)
        #pragma unroll
        for (int rg = 0; rg < 4; rg++) {
          const int row = mbase + i*16 + quad*4 + rg;
          const int col = nbase + j*16 + m0;
          gp[row*128 + col] = acc[i][j][rg];
        }
  } else {
    #pragma unroll
    for (int i = 0; i < 4; i++)
      #pragma unroll
      for (int j = 0; j < 4; j++)
        #pragma unroll
        for (int rg = 0; rg < 4; rg++) {
          const int row = i0 + mbase + i*16 + quad*4 + rg;
          const int col = j0 + nbase + j*16 + m0;
          atomicAdd(&G[((size_t)b*TWOC + row)*TWOC + col], acc[i][j][rg]);
        }
  }
}

// Reduce the 32 K-chunk partials into G; t==1 also writes the mirror
// (G symmetric: G01 = G10^T), removing the pmirror dependency.
__global__ __launch_bounds__(256) void greduce_kernel(
    const float* __restrict__ GP, float* __restrict__ G)
{
  const int t   = blockIdx.y;
  const int b   = blockIdx.z;
  const int idx = blockIdx.x * 256 + threadIdx.x;   // 0..16383
  const float* gp = GP + ((size_t)(b*3 + t)*NCHUNK) * (128*128) + idx;
  float s = 0.f;
  #pragma unroll
  for (int k = 0; k < NCHUNK; k++) s += gp[(size_t)k * (128*128)];
  const int i0 = (t == 0) ? 0 : CH;
  const int j0 = (t == 2) ? CH : 0;
  const int row = idx >> 7, col = idx & 127;
  G[((size_t)b*TWOC + i0 + row)*TWOC + j0 + col] = s;
  if (t == 1)
    G[((size_t)b*TWOC + col)*TWOC + CH + row] = s;   // mirror G01 = G10^T
}

// -----------------------------------------------------------------
// att_row_kernel: fused H -> E -> relu(t1) -> relu(t2) -> softmax.
// One block per (row i, batch b). P folded in (computed from S).
// Replaces h/e/t1/t2/softmax kernels (4 fewer launches, no H/E/E1/E2
// global round-trips).
// -----------------------------------------------------------------
__global__ __launch_bounds__(256) void att_row_kernel(
    const float* __restrict__ G, const float* __restrict__ S,
    const float* __restrict__ qw, const float* __restrict__ kw,
    const float* __restrict__ qb, const float* __restrict__ kb,
    const float* __restrict__ t1w, const float* __restrict__ t1b,
    const float* __restrict__ t2w, const float* __restrict__ t2b,
    float* __restrict__ ATT)
{
  const int i   = blockIdx.x;   // 0..255
  const int b   = blockIdx.y;
  const int tid = threadIdx.x;  // 0..255

  __shared__ float Hs[TWOC];
  __shared__ float Es[TWOC];
  __shared__ float E1s[TWOC];
  __shared__ float Ss[TWOC];
  __shared__ float red[8];

  Ss[tid] = S[b*TWOC + tid];

  const int jbase = (i < CH) ? 0 : CH;
  const float* wi  = (i < CH) ? (qw + (size_t)i*CH) : (kw + (size_t)(i-CH)*CH);
  const float bci  = (i < CH) ? qb[i] : kb[i-CH];

  // H[k] = sum_j wi[j] * G[jbase+j][k]  (coalesced row reads of G)
  float hacc = 0.f;
  const float* gcol = G + ((size_t)b*TWOC + jbase)*TWOC + tid;
  for (int j2 = 0; j2 < CH; j2++) hacc = fmaf(wi[j2], gcol[(size_t)j2*TWOC], hacc);
  Hs[tid] = hacc;
  __syncthreads();

  // E[j] = (H_seg . w_j + bci*Pj + bcj*Pi + N*bci*bcj) / 16
  {
    const int j = tid;
    const float* wj = (j < CH) ? (qw + (size_t)j*CH) : (kw + (size_t)(j-CH)*CH);
    const float bcj = (j < CH) ? qb[j] : kb[j-CH];
    const float* hseg = Hs + ((j < CH) ? 0 : CH);
    const float* ssj  = Ss + ((j < CH) ? 0 : CH);
    const float* ssi  = Ss + ((i < CH) ? 0 : CH);
    const float4* w4  = (const float4*)wj;
    const float4* wi4 = (const float4*)wi;
    float eacc = 0.f, pj = 0.f, pi = 0.f;
    for (int k = 0; k < CH/4; k++) {
      const float4 wv  = w4[k];
      const float4 hv  = *(const float4*)&hseg[k*4];
      const float4 sv  = *(const float4*)&ssj[k*4];
      const float4 wiv = wi4[k];
      const float4 siv = *(const float4*)&ssi[k*4];
      eacc += hv.x*wv.x + hv.y*wv.y + hv.z*wv.z + hv.w*wv.w;
      pj   += sv.x*wv.x + sv.y*wv.y + sv.z*wv.z + sv.w*wv.w;
      pi   += siv.x*wiv.x + siv.y*wiv.y + siv.z*wiv.z + siv.w*wiv.w;
    }
    eacc += pi*bcj + bci*pj + (float)NPTS * bci * bcj;
    Es[j] = eacc * (1.0f/16.0f);
  }
  __syncthreads();

  // E1[j] = relu(E . t1w_j + t1b_j)
  {
    float a1 = t1b[tid];
    const float4* wr = (const float4*)(t1w + (size_t)tid*TWOC);
    for (int k = 0; k < TWOC/4; k++) {
      const float4 wv = wr[k];
      const float4 ev = *(const float4*)&Es[k*4];
      a1 += ev.x*wv.x + ev.y*wv.y + ev.z*wv.z + ev.w*wv.w;
    }
    E1s[tid] = fmaxf(a1, 0.f);
  }
  __syncthreads();

  // E2[j] = relu(E1 . t2w_j + t2b_j)  (j < 128), then softmax over row.
  float e2 = 0.f;
  if (tid < CH) {
    float a2 = t2b[tid];
    const float4* wr = (const float4*)(t2w + (size_t)tid*TWOC);
    for (int k = 0; k < TWOC/4; k++) {
      const float4 wv = wr[k];
      const float4 ev = *(const float4*)&E1s[k*4];
      a2 += ev.x*wv.x + ev.y*wv.y + ev.z*wv.z + ev.w*wv.w;
    }
    e2 = fmaxf(a2, 0.f);
  }

  const int lane = tid & 63, wv_ = tid >> 6;
  float m = (tid < CH) ? e2 : -1e30f;
  for (int off = 32; off > 0; off >>= 1) m = fmaxf(m, __shfl_xor(m, off));
  if (lane == 0) red[wv_] = m;
  __syncthreads();
  m = fmaxf(red[0], red[1]);

  float ex = (tid < CH) ? expf(e2 - m) : 0.f;
  float sum = ex;
  for (int off = 32; off > 0; off >>= 1) sum += __shfl_xor(sum, off);
  if (lane == 0) red[4 + wv_] = sum;
  __syncthreads();
  sum = red[4] + red[5];

  if (tid < CH)
    ATT[((size_t)b*TWOC + i)*CH + tid] = ex / sum;
}

// out = M(128x256,f16) @ Z(256xN,f16) + C0 via MFMA.
// B-stage transpose writes now XOR-swizzle the d-granule with (n>>3)&7:
// was a 16-way bank conflict (n*36 ≡ const mod 32 across lanes), now 4-way.
__global__ __launch_bounds__(256) void out_mfma(
    const _Float16* __restrict__ Zh, const _Float16* __restrict__ Mh,
    const float* __restrict__ C0, float* __restrict__ out)
{
  const int n0 = blockIdx.x * 128;
  const int b  = blockIdx.y;

  __shared__ __align__(16) _Float16 As[128*64];   // M slice [c][d], swizzled
  __shared__ __align__(16) _Float16 Bs[128*72];   // Z^T slice [n][d], pad 72, granule-XOR

  const int tid   = threadIdx.x;
  const int lane  = tid & 63;
  const int wave  = tid >> 6;
  const int mbase = (wave & 1) * 64;   // c
  const int nbase = (wave >> 1) * 64;  // n
  const int m0    = lane & 15;
  const int quad  = lane >> 4;

  const int srow  = tid >> 1;
  const int gbase = (tid & 1) * 4;
  const int dl    = tid >> 4;          // 0..15
  const int ng    = tid & 15;          // 0..15

  floatx4 acc[4][4];
  #pragma unroll
  for (int i = 0; i < 4; i++)
    #pragma unroll
    for (int j = 0; j < 4; j++) acc[i][j] = (floatx4){0.f,0.f,0.f,0.f};

  for (int d0 = 0; d0 < TWOC; d0 += 64) {
    __syncthreads();
    #pragma unroll
    for (int q = 0; q < 4; q++) {
      const int g  = gbase + q;
      const int gp = g ^ (srow & 7);
      *(uint4*)&As[(size_t)(srow*8 + gp)*8] =
          *(const uint4*)(Mh + ((size_t)b*CH + srow)*TWOC + d0 + g*8);
    }
    // stage B transposed: Bs[n][d-granule ^ (n>>3)&7] <- Zh[d0+d][n0+n]
    #pragma unroll
    for (int ds = 0; ds < 4; ds++) {
      const int d    = dl + ds*16;      // 0..63
      const int gd   = d >> 3;
      const int dlow = d & 7;
      union { uint4 u; _Float16 h[8]; } v;
      v.u = *(const uint4*)(Zh + ((size_t)b*TWOC + d0 + d)*NPTS + n0 + ng*8);
      #pragma unroll
      for (int e = 0; e < 8; e++) {
        const int n  = ng*8 + e;
        const int pg = gd ^ (ng & 7);   // ng == n>>3
        Bs[(size_t)n*72 + pg*8 + dlow] = v.h[e];
      }
    }
    __syncthreads();
    #pragma unroll
    for (int ks = 0; ks < 2; ks++) {
      half8 af[4], bf[4];
      #pragma unroll
      for (int i = 0; i < 4; i++) {
        const int ra = mbase + i*16 + m0;
        const int ga = (ks*4 + quad) ^ (ra & 7);
        af[i] = *(const half8*)&As[(size_t)(ra*8 + ga)*8];
        const int rn  = nbase + i*16 + m0;
        const int g   = ks*4 + quad;
        const int pgr = g ^ ((rn >> 3) & 7);
        bf[i] = *(const half8*)&Bs[(size_t)rn*72 + pgr*8];
      }
      #pragma unroll
      for (int i = 0; i < 4; i++)
        #pragma unroll
        for (int j = 0; j < 4; j++)
          acc[i][j] = __builtin_amdgcn_mfma_f32_16x16x32_f16(af[i], bf[j], acc[i][j], 0, 0, 0);
    }
  }

  #pragma unroll
  for (int i = 0; i < 4; i++) {
    #pragma unroll
    for (int rg = 0; rg < 4; rg++) {
      const int c  = mbase + i*16 + quad*4 + rg;
      const float cv = C0[b*CH + c];
      #pragma unroll
      for (int j = 0; j < 4; j++) {
        const int n = n0 + nbase + j*16 + m0;
        out[((size_t)b*CH + c)*NPTS + n] = acc[i][j][rg] + cv;
      }
    }
  }
}

// mout variant writing f16 M
__global__ void mout_f16_kernel(const float* __restrict__ ATT, const float* __restrict__ v1w,
                                const float* __restrict__ v2w, const float* __restrict__ v1b,
                                const float* __restrict__ v2b, _Float16* __restrict__ Mh,
                                float* __restrict__ C0)
{
  const int c = blockIdx.x, b = blockIdx.y, j = threadIdx.x;  // j: 0..255
  __shared__ float acol[TWOC];
  acol[j] = ATT[((size_t)b*TWOC + j)*CH + c];
  __syncthreads();
  float acc = 0.f;
  if (j < CH) {
    for (int d = 0; d < CH; d++) acc = fmaf(acol[d], v2w[(size_t)d*CH + j], acc);
  } else {
    const int jj = j - CH;
    for (int d = 0; d < CH; d++) acc = fmaf(acol[CH + d], v1w[(size_t)d*CH + jj], acc);
  }
  Mh[((size_t)b*CH + c)*TWOC + j] = (_Float16)acc;
  if (j == 0) {
    float s = 0.f;
    for (int d = 0; d < CH; d++) s += acol[d]*v2b[d] + acol[CH+d]*v1b[d];
    C0[b*CH + c] = s;
  }
}

// pmirror: mirror G01 = G10^T (only needed when greduce doesn't run)
__global__ void pmirror_kernel(const float* __restrict__ S, const float* __restrict__ qw,
                               const float* __restrict__ kw, float* __restrict__ P,
                               float* __restrict__ G)
{
  const int b = blockIdx.x;
  const int tid = threadIdx.x;
  float* Gb = G + (size_t)b * TWOC * TWOC;
  for (int idx = tid; idx < CH*CH; idx += 256) {
    const int i2 = idx >> 7, j2 = idx & 127;
    Gb[(size_t)i2*TWOC + CH + j2] = Gb[(size_t)(CH + j2)*TWOC + i2];
  }
}

// =================================================================
// FALLBACK PATH (fp32 kernels, used only if ws too small)
// =================================================================
__global__ __launch_bounds__(256) void gram_kernel(
    const float* __restrict__ x, const float* __restrict__ y,
    float* __restrict__ G, float* __restrict__ S)
{
  const int t  = blockIdx.x;
  const int kc = blockIdx.y;
  const int b  = blockIdx.z;
  const float* Ab = (t == 0) ? y : x;
  const float* Bb = (t == 2) ? x : y;
  const int growA = (t == 0) ? 0 : CH;
  const int gcolB = (t == 2) ? CH : 0;
  const float* Ap = Ab + (size_t)b * CH * NPTS + (size_t)kc * KC;
  const float* Bp = Bb + (size_t)b * CH * NPTS + (size_t)kc * KC;

  __shared__ __align__(16) float As[8][128];
  __shared__ __align__(16) float Bs[8][128];

  const int tid  = threadIdx.x;
  const int ti   = tid >> 4;
  const int tj   = tid & 15;
  const int lrow = tid >> 1;
  const int lk4  = (tid & 1) * 4;

  const float* arow = Ap + (size_t)lrow * NPTS + lk4;
  const float* brow = Bp + (size_t)lrow * NPTS + lk4;

  float acc[8][8];
  #pragma unroll
  for (int i = 0; i < 8; i++)
    #pragma unroll
    for (int j = 0; j < 8; j++) acc[i][j] = 0.f;
  float asum = 0.f;

  for (int k0 = 0; k0 < KC; k0 += 8) {
    const float4 av = *(const float4*)(arow + k0);
    const float4 bv = *(const float4*)(brow + k0);
    __syncthreads();
    As[lk4+0][lrow] = av.x; As[lk4+1][lrow] = av.y;
    As[lk4+2][lrow] = av.z; As[lk4+3][lrow] = av.w;
    Bs[lk4+0][lrow] = bv.x; Bs[lk4+1][lrow] = bv.y;
    Bs[lk4+2][lrow] = bv.z; Bs[lk4+3][lrow] = bv.w;
    asum += av.x + av.y + av.z + av.w;
    __syncthreads();
    #pragma unroll
    for (int kk = 0; kk < 8; kk++) {
      float a[8], bb[8];
      *(float4*)&a[0]  = *(const float4*)&As[kk][ti*8];
      *(float4*)&a[4]  = *(const float4*)&As[kk][ti*8+4];
      *(float4*)&bb[0] = *(const float4*)&Bs[kk][tj*8];
      *(float4*)&bb[4] = *(const float4*)&Bs[kk][tj*8+4];
      #pragma unroll
      for (int ii = 0; ii < 8; ii++)
        #pragma unroll
        for (int jj = 0; jj < 8; jj++)
          acc[ii][jj] = fmaf(a[ii], bb[jj], acc[ii][jj]);
    }
  }

  float* Gp = G + ((size_t)b * TWOC + growA) * TWOC + gcolB;
  #pragma unroll
  for (int ii = 0; ii < 8; ii++)
    #pragma unroll
    for (int jj = 0; jj < 8; jj++)
      atomicAdd(&Gp[(size_t)(ti*8+ii) * TWOC + (tj*8+jj)], acc[ii][jj]);

  if (t == 0)      atomicAdd(&S[b*TWOC + lrow],      asum);
  else if (t == 2) atomicAdd(&S[b*TWOC + CH + lrow], asum);
}

__global__ void mout_f32_kernel(const float* __restrict__ ATT, const float* __restrict__ v1w,
                                const float* __restrict__ v2w, const float* __restrict__ v1b,
                                const float* __restrict__ v2b, float* __restrict__ M,
                                float* __restrict__ C0)
{
  const int c = blockIdx.x, b = blockIdx.y, j = threadIdx.x;
  __shared__ float acol[TWOC];
  acol[j] = ATT[((size_t)b*TWOC + j)*CH + c];
  __syncthreads();
  float acc = 0.f;
  if (j < CH) {
    for (int d = 0; d < CH; d++) acc = fmaf(acol[d], v2w[(size_t)d*CH + j], acc);
  } else {
    const int jj = j - CH;
    for (int d = 0; d < CH; d++) acc = fmaf(acol[CH + d], v1w[(size_t)d*CH + jj], acc);
  }
  M[((size_t)b*CH + c)*TWOC + j] = acc;
  if (j == 0) {
    float s = 0.f;
    for (int d = 0; d < CH; d++) s += acol[d]*v2b[d] + acol[CH+d]*v1b[d];
    C0[b*CH + c] = s;
  }
}

__global__ __launch_bounds__(256) void out_kernel(
    const float* __restrict__ x, const float* __restrict__ y,
    const float* __restrict__ M, const float* __restrict__ C0,
    float* __restrict__ out)
{
  const int b  = blockIdx.y;
  const int n0 = blockIdx.x * 64;
  const int tid = threadIdx.x;
  const int tc = tid & 15;
  const int tn = tid >> 4;

  __shared__ __align__(16) float Ms[64][128];
  __shared__ __align__(16) float Zs[64][64];

  float acc[8][4];
  #pragma unroll
  for (int i = 0; i < 8; i++)
    #pragma unroll
    for (int j = 0; j < 4; j++) acc[i][j] = 0.f;

  const float* Mb = M + (size_t)b * CH * TWOC;

  for (int chunk = 0; chunk < 4; chunk++) {
    const int kbase = chunk * 64;
    const float* Zsrc = ((chunk < 2) ? y : x) + (size_t)b * CH * NPTS
                        + (size_t)((chunk & 1) * 64) * NPTS;
    __syncthreads();
    {
      const int c   = tid >> 1;
      const int kb2 = (tid & 1) * 32;
      const float* mr = Mb + (size_t)c * TWOC + kbase + kb2;
      #pragma unroll
      for (int q = 0; q < 8; q++) {
        const float4 v = *(const float4*)(mr + q*4);
        Ms[kb2 + q*4 + 0][c] = v.x;
        Ms[kb2 + q*4 + 1][c] = v.y;
        Ms[kb2 + q*4 + 2][c] = v.z;
        Ms[kb2 + q*4 + 3][c] = v.w;
      }
      const int kk  = tid >> 2;
      const int nb4 = (tid & 3) * 4;
      const float* zr = Zsrc + (size_t)kk * NPTS + n0 + nb4;
      #pragma unroll
      for (int q = 0; q < 4; q++)
        *(float4*)&Zs[kk][nb4 + q*16] = *(const float4*)(zr + q*16);
    }
    __syncthreads();
    #pragma unroll 8
    for (int kk = 0; kk < 64; kk++) {
      float a[8], zz[4];
      *(float4*)&a[0]  = *(const float4*)&Ms[kk][tc*8];
      *(float4*)&a[4]  = *(const float4*)&Ms[kk][tc*8+4];
      *(float4*)&zz[0] = *(const float4*)&Zs[kk][tn*4];
      #pragma unroll
      for (int ii = 0; ii < 8; ii++)
        #pragma unroll
        for (int jj = 0; jj < 4; jj++)
          acc[ii][jj] = fmaf(a[ii], zz[jj], acc[ii][jj]);
    }
  }

  #pragma unroll
  for (int ii = 0; ii < 8; ii++) {
    const int c = tc*8 + ii;
    const float cv = C0[b*CH + c];
    float4 o;
    o.x = acc[ii][0] + cv; o.y = acc[ii][1] + cv;
    o.z = acc[ii][2] + cv; o.w = acc[ii][3] + cv;
    *(float4*)&out[((size_t)b*CH + c)*NPTS + n0 + tn*4] = o;
  }
}

// -----------------------------------------------------------------
extern "C" void kernel_launch(void* const* d_in, const int* in_sizes, int n_in,
                              void* d_out, int out_size, void* d_ws, size_t ws_size,
                              hipStream_t stream)
{
  const float* x   = (const float*)d_in[0];
  const float* y   = (const float*)d_in[1];
  const float* qw  = (const float*)d_in[2];
  const float* qb  = (const float*)d_in[3];
  const float* kw  = (const float*)d_in[4];
  const float* kb  = (const float*)d_in[5];
  const float* v1w = (const float*)d_in[6];
  const float* v1b = (const float*)d_in[7];
  const float* v2w = (const float*)d_in[8];
  const float* v2b = (const float*)d_in[9];
  const float* t1w = (const float*)d_in[10];
  const float* t1b = (const float*)d_in[11];
  const float* t2w = (const float*)d_in[12];
  const float* t2b = (const float*)d_in[13];

  float* ws = (float*)d_ws;
  float* G  = ws + OFF_G;
  float* S  = ws + OFF_S;
  float* P  = ws + OFF_P;
  float* AT = ws + OFF_AT;
  float* C0 = ws + OFF_C0;
  float* outp = (float*)d_out;

  // zero G and S
  hipMemsetAsync(d_ws, 0, (OFF_S + 2048) * sizeof(float), stream);

  if (ws_size >= WS_NEED_NEW) {
    _Float16* Mh = (_Float16*)(ws + OFF_MH);
    _Float16* Zh = (_Float16*)(ws + OFF_ZH);
    const bool useGP = (ws_size >= WS_NEED_V3);
    float* GP = useGP ? (ws + OFF_GP) : nullptr;

    convert_kernel<<<dim3(NPTS/4096, TWOC, NB), 256, 0, stream>>>(x, y, Zh, S);
    gram_mfma3    <<<dim3(3 * NCHUNK * NB),     256, 0, stream>>>(Zh, G, GP);
    if (useGP)
      greduce_kernel<<<dim3(64, 3, NB),         256, 0, stream>>>(GP, G);
    else
      pmirror_kernel<<<dim3(NB),                256, 0, stream>>>(S, qw, kw, P, G);
    att_row_kernel<<<dim3(TWOC, NB),            256, 0, stream>>>(G, S, qw, kw, qb, kb,
                                                                  t1w, t1b, t2w, t2b, AT);
    mout_f16_kernel<<<dim3(CH, NB),             256, 0, stream>>>(AT, v1w, v2w, v1b, v2b, Mh, C0);
    out_mfma      <<<dim3(NPTS/128, NB),        256, 0, stream>>>(Zh, Mh, C0, outp);
  } else {
    float* Mo = ws + OFF_MH;
    gram_kernel   <<<dim3(3, NPTS/KC, NB), 256, 0, stream>>>(x, y, G, S);
    pmirror_kernel<<<dim3(NB),             256, 0, stream>>>(S, qw, kw, P, G);
    att_row_kernel<<<dim3(TWOC, NB),       256, 0, stream>>>(G, S, qw, kw, qb, kb,
                                                             t1w, t1b, t2w, t2b, AT);
    mout_f32_kernel<<<dim3(CH, NB),        256, 0, stream>>>(AT, v1w, v2w, v1b, v2b, Mo, C0);
    out_kernel    <<<dim3(NPTS/64, NB),    256, 0, stream>>>(x, y, Mo, C0, outp);
  }
}

// Round 3
// 582.043 us; speedup vs baseline: 1.3722x; 1.0575x over previous
//
#include <hip/hip_runtime.h>

// Problem constants
constexpr int CH   = 128;    // C
constexpr int TWOC = 256;    // 2C
constexpr int NPTS = 32768;  // N
constexpr int NB   = 8;      // B
constexpr int KC   = 2048;   // K-chunk for fallback fp32 gram

// gram_mfma3 geometry
constexpr int KC3    = 1024; // K per block (32 chunks)
constexpr int KSTAGE = 128;  // K per LDS stage (256B per row burst)
constexpr int NST    = KC3 / KSTAGE;  // 8 stages
constexpr int NCHUNK = NPTS / KC3;    // 32

typedef _Float16 half8 __attribute__((ext_vector_type(8)));
typedef float floatx4 __attribute__((ext_vector_type(4)));

// ---------------- Workspace layout (float offsets) ----------------
constexpr size_t OFF_G  = 0;
constexpr size_t OFF_S  = 524288;
constexpr size_t OFF_P  = 526336;
constexpr size_t OFF_H  = 528384;   // now hosts transposed weights (131072 floats used)
constexpr size_t OFF_AT = 2363392;
constexpr size_t OFF_C0 = 2625536;
constexpr size_t OFF_MH = 2626560;
constexpr size_t OFF_ZH = 2757632;
constexpr size_t OFF_GP = OFF_ZH + 33554432;               // partial G tiles
constexpr size_t GP_LEN = (size_t)3 * NB * NCHUNK * 128 * 128;  // 12.58M floats
constexpr size_t WS_NEED_NEW = (OFF_ZH + 33554432) * sizeof(float);  // ~145.2 MB
constexpr size_t WS_NEED_V3  = (OFF_GP + GP_LEN) * sizeof(float);    // ~195.6 MB

// transposed-weight sub-offsets inside OFF_H
constexpr size_t OFF_WQKT = OFF_H;                 // 128*256 = 32768
constexpr size_t OFF_T1T  = OFF_H + 32768;         // 256*256 = 65536
constexpr size_t OFF_T2T  = OFF_H + 32768 + 65536; // 256*128 = 32768

// =================================================================
// NEW PATH (f16 MFMA)
// =================================================================

// Convert: Z = [y; x] per batch -> f16, plus row sums S (atomic).
// Lane-contiguous float4 reads (1KB/wave/inst) + uint2 f16 writes.
__global__ __launch_bounds__(256) void convert_kernel(
    const float* __restrict__ x, const float* __restrict__ y,
    _Float16* __restrict__ Zh, float* __restrict__ S)
{
  const int seg = blockIdx.x;          // 0..7 (4096 elements each)
  const int r   = blockIdx.y;          // 0..255
  const int b   = blockIdx.z;
  const float* src = ((r < CH) ? (y + ((size_t)b*CH + r)*NPTS)
                               : (x + ((size_t)b*CH + (r-CH))*NPTS)) + (size_t)seg*4096;
  _Float16* dst = Zh + ((size_t)b*TWOC + r)*NPTS + (size_t)seg*4096;
  const int tid = threadIdx.x;

  float s = 0.f;
  #pragma unroll
  for (int it = 0; it < 4; it++) {
    const int idx = it*1024 + tid*4;
    const float4 v = *(const float4*)(src + idx);
    union { uint2 u; _Float16 h[4]; } p;
    p.h[0]=(_Float16)v.x; p.h[1]=(_Float16)v.y; p.h[2]=(_Float16)v.z; p.h[3]=(_Float16)v.w;
    *(uint2*)(dst + idx) = p.u;
    s += v.x + v.y + v.z + v.w;
  }

  for (int off = 32; off > 0; off >>= 1) s += __shfl_down(s, off);
  if ((tid & 63) == 0) atomicAdd(&S[b*TWOC + r], s);
}

// -----------------------------------------------------------------
// gram_mfma3: Gram via MFMA f16 (unchanged from round 2)
// -----------------------------------------------------------------
__global__ __launch_bounds__(256) void gram_mfma3(
    const _Float16* __restrict__ Zh, float* __restrict__ G, float* __restrict__ GP)
{
  __shared__ __align__(16) _Float16 As[2][128 * KSTAGE];
  __shared__ __align__(16) _Float16 Bs[2][128 * KSTAGE];

  const int hw    = blockIdx.x;        // 0..767
  const int xcd   = hw & 7;
  const int local = hw >> 3;           // 0..95
  const int t     = local % 3;         // tile: 0:(0,0) 1:(128,0) 2:(128,128)
  const int grp   = local / 3;         // 0..31
  const int gidx  = xcd * 32 + grp;    // 0..255
  const int kc    = gidx & 31;
  const int b     = gidx >> 5;

  const int i0 = (t == 0) ? 0 : CH;
  const int j0 = (t == 2) ? CH : 0;
  const _Float16* Ar = Zh + ((size_t)b*TWOC + i0)*NPTS + (size_t)kc*KC3;
  const _Float16* Br = Zh + ((size_t)b*TWOC + j0)*NPTS + (size_t)kc*KC3;

  const int tid   = threadIdx.x;
  const int lane  = tid & 63;
  const int wave  = tid >> 6;
  const int mbase = (wave & 1) * 64;
  const int nbase = (wave >> 1) * 64;
  const int m0    = lane & 15;
  const int quad  = lane >> 4;

#define STAGE(buf, k0)                                                        \
  {                                                                           \
    _Pragma("unroll")                                                         \
    for (int i = 0; i < 8; i++) {                                             \
      const int s = wave*512 + i*64 + lane;                                   \
      const int r = s >> 4;                                                   \
      const int g = s & 15;                                                   \
      const int gs = g ^ (r & 7);                                             \
      __builtin_amdgcn_global_load_lds(                                       \
        (const __attribute__((address_space(1))) void*)(Ar + (size_t)r*NPTS + (k0) + gs*8), \
        (__attribute__((address_space(3))) void*)&As[buf][(wave*512 + i*64)*8], \
        16, 0, 0);                                                            \
      __builtin_amdgcn_global_load_lds(                                       \
        (const __attribute__((address_space(1))) void*)(Br + (size_t)r*NPTS + (k0) + gs*8), \
        (__attribute__((address_space(3))) void*)&Bs[buf][(wave*512 + i*64)*8], \
        16, 0, 0);                                                            \
    }                                                                         \
  }

  floatx4 acc[4][4];
  #pragma unroll
  for (int i = 0; i < 4; i++)
    #pragma unroll
    for (int j = 0; j < 4; j++) acc[i][j] = (floatx4){0.f,0.f,0.f,0.f};

  STAGE(0, 0);

  int cur = 0;
  for (int st = 0; st < NST; ++st) {
    if (st + 1 < NST) {
      STAGE(cur ^ 1, (st + 1) * KSTAGE);
      asm volatile("s_waitcnt vmcnt(16)" ::: "memory");
    } else {
      asm volatile("s_waitcnt vmcnt(0)" ::: "memory");
    }
    __builtin_amdgcn_s_barrier();

    #pragma unroll
    for (int kk = 0; kk < 4; kk++) {
      half8 af[4], bf[4];
      #pragma unroll
      for (int i = 0; i < 4; i++) {
        const int ra = mbase + i*16 + m0;
        const int ga = (kk*4 + quad) ^ (ra & 7);
        af[i] = *(const half8*)&As[cur][ra*KSTAGE + ga*8];
        const int rb = nbase + i*16 + m0;
        const int gb = (kk*4 + quad) ^ (rb & 7);
        bf[i] = *(const half8*)&Bs[cur][rb*KSTAGE + gb*8];
      }
      #pragma unroll
      for (int i = 0; i < 4; i++)
        #pragma unroll
        for (int j = 0; j < 4; j++)
          acc[i][j] = __builtin_amdgcn_mfma_f32_16x16x32_f16(af[i], bf[j], acc[i][j], 0, 0, 0);
    }

    __builtin_amdgcn_s_barrier();
    cur ^= 1;
  }
#undef STAGE

  if (GP != nullptr) {
    float* gp = GP + (((size_t)(b*3 + t)*NCHUNK + kc) * (128*128));
    #pragma unroll
    for (int i = 0; i < 4; i++)
      #pragma unroll
      for (int j = 0; j < 4; j++)
        #pragma unroll
        for (int rg = 0; rg < 4; rg++) {
          const int row = mbase + i*16 + quad*4 + rg;
          const int col = nbase + j*16 + m0;
          gp[row*128 + col] = acc[i][j][rg];
        }
  } else {
    #pragma unroll
    for (int i = 0; i < 4; i++)
      #pragma unroll
      for (int j = 0; j < 4; j++)
        #pragma unroll
        for (int rg = 0; rg < 4; rg++) {
          const int row = i0 + mbase + i*16 + quad*4 + rg;
          const int col = j0 + nbase + j*16 + m0;
          atomicAdd(&G[((size_t)b*TWOC + row)*TWOC + col], acc[i][j][rg]);
        }
  }
}

// Reduce the 32 K-chunk partials into G; t==1 also writes the mirror.
__global__ __launch_bounds__(256) void greduce_kernel(
    const float* __restrict__ GP, float* __restrict__ G)
{
  const int t   = blockIdx.y;
  const int b   = blockIdx.z;
  const int idx = blockIdx.x * 256 + threadIdx.x;   // 0..16383
  const float* gp = GP + ((size_t)(b*3 + t)*NCHUNK) * (128*128) + idx;
  float s = 0.f;
  #pragma unroll
  for (int k = 0; k < NCHUNK; k++) s += gp[(size_t)k * (128*128)];
  const int i0 = (t == 0) ? 0 : CH;
  const int j0 = (t == 2) ? CH : 0;
  const int row = idx >> 7, col = idx & 127;
  G[((size_t)b*TWOC + i0 + row)*TWOC + j0 + col] = s;
  if (t == 1)
    G[((size_t)b*TWOC + col)*TWOC + CH + row] = s;   // mirror G01 = G10^T
}

// -----------------------------------------------------------------
// wtrans: one-time weight transposes so GEMV inner loops read weights
// lane-coalesced. wqkT[k][j] = concat(qw,kw)[j][k]; t1wT[k][j]; t2wT[k][j].
// grid 640 x 256 threads.
// -----------------------------------------------------------------
__global__ void wtrans_kernel(const float* __restrict__ qw, const float* __restrict__ kw,
                              const float* __restrict__ t1w, const float* __restrict__ t2w,
                              float* __restrict__ wqkT, float* __restrict__ t1wT,
                              float* __restrict__ t2wT)
{
  const int r = blockIdx.x;
  const int j = threadIdx.x;
  if (r < 128) {
    wqkT[(size_t)r*TWOC + j] = (j < CH) ? qw[(size_t)j*CH + r] : kw[(size_t)(j-CH)*CH + r];
  } else if (r < 384) {
    const int k = r - 128;
    t1wT[(size_t)k*TWOC + j] = t1w[(size_t)j*TWOC + k];
  } else {
    const int k = r - 384;
    if (j < CH) t2wT[(size_t)k*CH + j] = t2w[(size_t)j*TWOC + k];
  }
}

// P[b][i] = w_i . S[b][seg_i..]
__global__ void p_kernel(const float* __restrict__ S, const float* __restrict__ qw,
                         const float* __restrict__ kw, float* __restrict__ P)
{
  const int b = blockIdx.x;
  const int i = threadIdx.x;
  const float* w = (i < CH) ? (qw + (size_t)i*CH) : (kw + (size_t)(i-CH)*CH);
  const float* s = S + b*TWOC + ((i < CH) ? 0 : CH);
  float acc = 0.f;
  for (int k = 0; k < CH; k++) acc = fmaf(w[k], s[k], acc);
  P[b*TWOC + i] = acc;
}

// -----------------------------------------------------------------
// he_att_kernel: fused chain, lane-coalesced register-tiled GEMVs.
// One block per (8-row tile, batch): grid (32, 8) = 256 blocks, 256 thr.
// Phases: A = W.G  ->  E = A.WT + rank1  ->  E1 = relu(E.t1wT+b1)
//         -> E2 = relu(E1.t2wT+b2) -> softmax -> ATT.
// All weight reads are lane-contiguous (w*T[k][j], j = lane*4) from L2;
// row-operand reads are LDS broadcasts. ~34KB LDS.
// -----------------------------------------------------------------
__global__ __launch_bounds__(256) void he_att_kernel(
    const float* __restrict__ G, const float* __restrict__ P_,
    const float* __restrict__ qw, const float* __restrict__ kw,
    const float* __restrict__ qb, const float* __restrict__ kb,
    const float* __restrict__ wqkT, const float* __restrict__ t1wT,
    const float* __restrict__ t2wT, const float* __restrict__ t1b,
    const float* __restrict__ t2b, float* __restrict__ ATT)
{
  const int it = blockIdx.x;       // 0..31
  const int b  = blockIdx.y;
  const int i0 = it * 8;
  const bool hi = (i0 >= CH);
  const int jb = hi ? CH : 0;

  __shared__ float Ws[8][CH];      // 4KB  W rows of this tile
  __shared__ float As[8][TWOC];    // 8KB
  __shared__ float Es[8][TWOC];    // 8KB
  __shared__ float E1s[8][TWOC];   // 8KB
  __shared__ float E2s[8][CH];     // 4KB
  __shared__ float Ps[TWOC];       // 1KB
  __shared__ float Bc[TWOC];       // 1KB
  __shared__ float bci[8];

  const int tid = threadIdx.x;
  const int tx  = tid & 63;        // lane
  const int ty  = tid >> 6;        // wave 0..3
  const int r0  = ty * 2;
  const int r1  = r0 + 1;

  // load W rows (8 x 128 = 1024 floats), each thread one float4, coalesced
  {
    const int rr = tid >> 5;             // 0..7
    const int cc = (tid & 31) * 4;       // 0..124
    const float* wr = hi ? (kw + (size_t)(i0 - CH + rr)*CH)
                         : (qw + (size_t)(i0 + rr)*CH);
    *(float4*)&Ws[rr][cc] = *(const float4*)&wr[cc];
  }
  Ps[tid] = P_[b*TWOC + tid];
  Bc[tid] = (tid < CH) ? qb[tid] : kb[tid - CH];
  if (tid < 8) bci[tid] = hi ? kb[i0 - CH + tid] : qb[i0 + tid];
  __syncthreads();

  // ---------- Phase 1: A[r][k] = sum_j Ws[r][j] * G[jb+j][k] ----------
  {
    const float* gb = G + ((size_t)b*TWOC + jb)*TWOC + tx*4;
    floatx4 a0 = {0,0,0,0}, a1 = {0,0,0,0};
    #pragma unroll 4
    for (int j = 0; j < CH; j++) {
      const float4 g4 = *(const float4*)(gb + (size_t)j*TWOC);
      const float w0 = Ws[r0][j], w1 = Ws[r1][j];
      a0[0] = fmaf(w0, g4.x, a0[0]); a0[1] = fmaf(w0, g4.y, a0[1]);
      a0[2] = fmaf(w0, g4.z, a0[2]); a0[3] = fmaf(w0, g4.w, a0[3]);
      a1[0] = fmaf(w1, g4.x, a1[0]); a1[1] = fmaf(w1, g4.y, a1[1]);
      a1[2] = fmaf(w1, g4.z, a1[2]); a1[3] = fmaf(w1, g4.w, a1[3]);
    }
    *(floatx4*)&As[r0][tx*4] = a0;
    *(floatx4*)&As[r1][tx*4] = a1;
  }
  __syncthreads();

  // ---------- Phase 2: E[r][j] = sum_k As[r][sj+k]*wqkT[k][j] + rank1 ----------
  {
    const int jc = tx * 4;
    const int sj = (jc < CH) ? 0 : CH;
    const float* wt = wqkT + jc;
    floatx4 e0 = {0,0,0,0}, e1 = {0,0,0,0};
    #pragma unroll 4
    for (int k = 0; k < CH; k++) {
      const float4 w4 = *(const float4*)(wt + (size_t)k*TWOC);
      const float a0 = As[r0][sj + k], a1 = As[r1][sj + k];
      e0[0] = fmaf(a0, w4.x, e0[0]); e0[1] = fmaf(a0, w4.y, e0[1]);
      e0[2] = fmaf(a0, w4.z, e0[2]); e0[3] = fmaf(a0, w4.w, e0[3]);
      e1[0] = fmaf(a1, w4.x, e1[0]); e1[1] = fmaf(a1, w4.y, e1[1]);
      e1[2] = fmaf(a1, w4.z, e1[2]); e1[3] = fmaf(a1, w4.w, e1[3]);
    }
    const float4 pj = *(const float4*)&Ps[jc];
    const float4 bj = *(const float4*)&Bc[jc];
    const float pi0 = Ps[i0 + r0], pi1 = Ps[i0 + r1];
    const float bi0 = bci[r0],     bi1 = bci[r1];
    const float NN = (float)NPTS;
    floatx4 o0, o1;
    o0[0] = (e0[0] + bi0*pj.x + bj.x*pi0 + NN*bi0*bj.x) * (1.0f/16.0f);
    o0[1] = (e0[1] + bi0*pj.y + bj.y*pi0 + NN*bi0*bj.y) * (1.0f/16.0f);
    o0[2] = (e0[2] + bi0*pj.z + bj.z*pi0 + NN*bi0*bj.z) * (1.0f/16.0f);
    o0[3] = (e0[3] + bi0*pj.w + bj.w*pi0 + NN*bi0*bj.w) * (1.0f/16.0f);
    o1[0] = (e1[0] + bi1*pj.x + bj.x*pi1 + NN*bi1*bj.x) * (1.0f/16.0f);
    o1[1] = (e1[1] + bi1*pj.y + bj.y*pi1 + NN*bi1*bj.y) * (1.0f/16.0f);
    o1[2] = (e1[2] + bi1*pj.z + bj.z*pi1 + NN*bi1*bj.z) * (1.0f/16.0f);
    o1[3] = (e1[3] + bi1*pj.w + bj.w*pi1 + NN*bi1*bj.w) * (1.0f/16.0f);
    *(floatx4*)&Es[r0][jc] = o0;
    *(floatx4*)&Es[r1][jc] = o1;
  }
  __syncthreads();

  // ---------- Phase 3: E1[r][j] = relu(sum_k Es[r][k]*t1wT[k][j] + b1[j]) ----------
  {
    const int jc = tx * 4;
    const float* wt = t1wT + jc;
    floatx4 a0 = {0,0,0,0}, a1 = {0,0,0,0};
    #pragma unroll 4
    for (int k = 0; k < TWOC; k++) {
      const float4 w4 = *(const float4*)(wt + (size_t)k*TWOC);
      const float e0 = Es[r0][k], e1 = Es[r1][k];
      a0[0] = fmaf(e0, w4.x, a0[0]); a0[1] = fmaf(e0, w4.y, a0[1]);
      a0[2] = fmaf(e0, w4.z, a0[2]); a0[3] = fmaf(e0, w4.w, a0[3]);
      a1[0] = fmaf(e1, w4.x, a1[0]); a1[1] = fmaf(e1, w4.y, a1[1]);
      a1[2] = fmaf(e1, w4.z, a1[2]); a1[3] = fmaf(e1, w4.w, a1[3]);
    }
    const float4 b1v = *(const float4*)&t1b[jc];
    floatx4 o0, o1;
    o0[0] = fmaxf(a0[0] + b1v.x, 0.f); o0[1] = fmaxf(a0[1] + b1v.y, 0.f);
    o0[2] = fmaxf(a0[2] + b1v.z, 0.f); o0[3] = fmaxf(a0[3] + b1v.w, 0.f);
    o1[0] = fmaxf(a1[0] + b1v.x, 0.f); o1[1] = fmaxf(a1[1] + b1v.y, 0.f);
    o1[2] = fmaxf(a1[2] + b1v.z, 0.f); o1[3] = fmaxf(a1[3] + b1v.w, 0.f);
    *(floatx4*)&E1s[r0][jc] = o0;
    *(floatx4*)&E1s[r1][jc] = o1;
  }
  __syncthreads();

  // ---------- Phase 4: E2[r][j] = relu(sum_k E1s[r][k]*t2wT[k][j] + b2[j]) ----------
  {
    const int jc2 = (tid & 31) * 4;     // 0..127
    const int r   = tid >> 5;           // 0..7
    const float* wt = t2wT + jc2;
    floatx4 a = {0,0,0,0};
    #pragma unroll 4
    for (int k = 0; k < TWOC; k++) {
      const float4 w4 = *(const float4*)(wt + (size_t)k*CH);
      const float e = E1s[r][k];
      a[0] = fmaf(e, w4.x, a[0]); a[1] = fmaf(e, w4.y, a[1]);
      a[2] = fmaf(e, w4.z, a[2]); a[3] = fmaf(e, w4.w, a[3]);
    }
    const float4 b2v = *(const float4*)&t2b[jc2];
    floatx4 o;
    o[0] = fmaxf(a[0] + b2v.x, 0.f); o[1] = fmaxf(a[1] + b2v.y, 0.f);
    o[2] = fmaxf(a[2] + b2v.z, 0.f); o[3] = fmaxf(a[3] + b2v.w, 0.f);
    *(floatx4*)&E2s[r][jc2] = o;
  }
  __syncthreads();

  // ---------- Phase 5: softmax rows -> ATT ----------
  {
    const int l = tx;
    #pragma unroll
    for (int rr = 0; rr < 2; rr++) {
      const int r = ty*2 + rr;
      const float v0 = E2s[r][l], v1 = E2s[r][l + 64];
      float m = fmaxf(v0, v1);
      for (int off = 32; off > 0; off >>= 1) m = fmaxf(m, __shfl_xor(m, off));
      const float ex0 = expf(v0 - m), ex1 = expf(v1 - m);
      float s = ex0 + ex1;
      for (int off = 32; off > 0; off >>= 1) s += __shfl_xor(s, off);
      const float inv = 1.f / s;
      float* o = ATT + ((size_t)b*TWOC + i0 + r)*CH;
      o[l] = ex0 * inv;
      o[l + 64] = ex1 * inv;
    }
  }
}

// out = M(128x256,f16) @ Z(256xN,f16) + C0 via MFMA (unchanged).
__global__ __launch_bounds__(256) void out_mfma(
    const _Float16* __restrict__ Zh, const _Float16* __restrict__ Mh,
    const float* __restrict__ C0, float* __restrict__ out)
{
  const int n0 = blockIdx.x * 128;
  const int b  = blockIdx.y;

  __shared__ __align__(16) _Float16 As[128*64];   // M slice [c][d], swizzled
  __shared__ __align__(16) _Float16 Bs[128*72];   // Z^T slice [n][d], pad 72, granule-XOR

  const int tid   = threadIdx.x;
  const int lane  = tid & 63;
  const int wave  = tid >> 6;
  const int mbase = (wave & 1) * 64;   // c
  const int nbase = (wave >> 1) * 64;  // n
  const int m0    = lane & 15;
  const int quad  = lane >> 4;

  const int srow  = tid >> 1;
  const int gbase = (tid & 1) * 4;
  const int dl    = tid >> 4;          // 0..15
  const int ng    = tid & 15;          // 0..15

  floatx4 acc[4][4];
  #pragma unroll
  for (int i = 0; i < 4; i++)
    #pragma unroll
    for (int j = 0; j < 4; j++) acc[i][j] = (floatx4){0.f,0.f,0.f,0.f};

  for (int d0 = 0; d0 < TWOC; d0 += 64) {
    __syncthreads();
    #pragma unroll
    for (int q = 0; q < 4; q++) {
      const int g  = gbase + q;
      const int gp = g ^ (srow & 7);
      *(uint4*)&As[(size_t)(srow*8 + gp)*8] =
          *(const uint4*)(Mh + ((size_t)b*CH + srow)*TWOC + d0 + g*8);
    }
    #pragma unroll
    for (int ds = 0; ds < 4; ds++) {
      const int d    = dl + ds*16;      // 0..63
      const int gd   = d >> 3;
      const int dlow = d & 7;
      union { uint4 u; _Float16 h[8]; } v;
      v.u = *(const uint4*)(Zh + ((size_t)b*TWOC + d0 + d)*NPTS + n0 + ng*8);
      #pragma unroll
      for (int e = 0; e < 8; e++) {
        const int n  = ng*8 + e;
        const int pg = gd ^ (ng & 7);
        Bs[(size_t)n*72 + pg*8 + dlow] = v.h[e];
      }
    }
    __syncthreads();
    #pragma unroll
    for (int ks = 0; ks < 2; ks++) {
      half8 af[4], bf[4];
      #pragma unroll
      for (int i = 0; i < 4; i++) {
        const int ra = mbase + i*16 + m0;
        const int ga = (ks*4 + quad) ^ (ra & 7);
        af[i] = *(const half8*)&As[(size_t)(ra*8 + ga)*8];
        const int rn  = nbase + i*16 + m0;
        const int g   = ks*4 + quad;
        const int pgr = g ^ ((rn >> 3) & 7);
        bf[i] = *(const half8*)&Bs[(size_t)rn*72 + pgr*8];
      }
      #pragma unroll
      for (int i = 0; i < 4; i++)
        #pragma unroll
        for (int j = 0; j < 4; j++)
          acc[i][j] = __builtin_amdgcn_mfma_f32_16x16x32_f16(af[i], bf[j], acc[i][j], 0, 0, 0);
    }
  }

  #pragma unroll
  for (int i = 0; i < 4; i++) {
    #pragma unroll
    for (int rg = 0; rg < 4; rg++) {
      const int c  = mbase + i*16 + quad*4 + rg;
      const float cv = C0[b*CH + c];
      #pragma unroll
      for (int j = 0; j < 4; j++) {
        const int n = n0 + nbase + j*16 + m0;
        out[((size_t)b*CH + c)*NPTS + n] = acc[i][j][rg] + cv;
      }
    }
  }
}

// mout variant writing f16 M
__global__ void mout_f16_kernel(const float* __restrict__ ATT, const float* __restrict__ v1w,
                                const float* __restrict__ v2w, const float* __restrict__ v1b,
                                const float* __restrict__ v2b, _Float16* __restrict__ Mh,
                                float* __restrict__ C0)
{
  const int c = blockIdx.x, b = blockIdx.y, j = threadIdx.x;  // j: 0..255
  __shared__ float acol[TWOC];
  acol[j] = ATT[((size_t)b*TWOC + j)*CH + c];
  __syncthreads();
  float acc = 0.f;
  if (j < CH) {
    for (int d = 0; d < CH; d++) acc = fmaf(acol[d], v2w[(size_t)d*CH + j], acc);
  } else {
    const int jj = j - CH;
    for (int d = 0; d < CH; d++) acc = fmaf(acol[CH + d], v1w[(size_t)d*CH + jj], acc);
  }
  Mh[((size_t)b*CH + c)*TWOC + j] = (_Float16)acc;
  if (j == 0) {
    float s = 0.f;
    for (int d = 0; d < CH; d++) s += acol[d]*v2b[d] + acol[CH+d]*v1b[d];
    C0[b*CH + c] = s;
  }
}

// pmirror: mirror G01 = G10^T (only needed when greduce doesn't run)
__global__ void pmirror_kernel(float* __restrict__ G)
{
  const int b = blockIdx.x;
  const int tid = threadIdx.x;
  float* Gb = G + (size_t)b * TWOC * TWOC;
  for (int idx = tid; idx < CH*CH; idx += 256) {
    const int i2 = idx >> 7, j2 = idx & 127;
    Gb[(size_t)i2*TWOC + CH + j2] = Gb[(size_t)(CH + j2)*TWOC + i2];
  }
}

// =================================================================
// FALLBACK PATH (fp32 kernels, used only if ws too small)
// =================================================================
__global__ __launch_bounds__(256) void gram_kernel(
    const float* __restrict__ x, const float* __restrict__ y,
    float* __restrict__ G, float* __restrict__ S)
{
  const int t  = blockIdx.x;
  const int kc = blockIdx.y;
  const int b  = blockIdx.z;
  const float* Ab = (t == 0) ? y : x;
  const float* Bb = (t == 2) ? x : y;
  const int growA = (t == 0) ? 0 : CH;
  const int gcolB = (t == 2) ? CH : 0;
  const float* Ap = Ab + (size_t)b * CH * NPTS + (size_t)kc * KC;
  const float* Bp = Bb + (size_t)b * CH * NPTS + (size_t)kc * KC;

  __shared__ __align__(16) float As[8][128];
  __shared__ __align__(16) float Bs[8][128];

  const int tid  = threadIdx.x;
  const int ti   = tid >> 4;
  const int tj   = tid & 15;
  const int lrow = tid >> 1;
  const int lk4  = (tid & 1) * 4;

  const float* arow = Ap + (size_t)lrow * NPTS + lk4;
  const float* brow = Bp + (size_t)lrow * NPTS + lk4;

  float acc[8][8];
  #pragma unroll
  for (int i = 0; i < 8; i++)
    #pragma unroll
    for (int j = 0; j < 8; j++) acc[i][j] = 0.f;
  float asum = 0.f;

  for (int k0 = 0; k0 < KC; k0 += 8) {
    const float4 av = *(const float4*)(arow + k0);
    const float4 bv = *(const float4*)(brow + k0);
    __syncthreads();
    As[lk4+0][lrow] = av.x; As[lk4+1][lrow] = av.y;
    As[lk4+2][lrow] = av.z; As[lk4+3][lrow] = av.w;
    Bs[lk4+0][lrow] = bv.x; Bs[lk4+1][lrow] = bv.y;
    Bs[lk4+2][lrow] = bv.z; Bs[lk4+3][lrow] = bv.w;
    asum += av.x + av.y + av.z + av.w;
    __syncthreads();
    #pragma unroll
    for (int kk = 0; kk < 8; kk++) {
      float a[8], bb[8];
      *(float4*)&a[0]  = *(const float4*)&As[kk][ti*8];
      *(float4*)&a[4]  = *(const float4*)&As[kk][ti*8+4];
      *(float4*)&bb[0] = *(const float4*)&Bs[kk][tj*8];
      *(float4*)&bb[4] = *(const float4*)&Bs[kk][tj*8+4];
      #pragma unroll
      for (int ii = 0; ii < 8; ii++)
        #pragma unroll
        for (int jj = 0; jj < 8; jj++)
          acc[ii][jj] = fmaf(a[ii], bb[jj], acc[ii][jj]);
    }
  }

  float* Gp = G + ((size_t)b * TWOC + growA) * TWOC + gcolB;
  #pragma unroll
  for (int ii = 0; ii < 8; ii++)
    #pragma unroll
    for (int jj = 0; jj < 8; jj++)
      atomicAdd(&Gp[(size_t)(ti*8+ii) * TWOC + (tj*8+jj)], acc[ii][jj]);

  if (t == 0)      atomicAdd(&S[b*TWOC + lrow],      asum);
  else if (t == 2) atomicAdd(&S[b*TWOC + CH + lrow], asum);
}

__global__ void mout_f32_kernel(const float* __restrict__ ATT, const float* __restrict__ v1w,
                                const float* __restrict__ v2w, const float* __restrict__ v1b,
                                const float* __restrict__ v2b, float* __restrict__ M,
                                float* __restrict__ C0)
{
  const int c = blockIdx.x, b = blockIdx.y, j = threadIdx.x;
  __shared__ float acol[TWOC];
  acol[j] = ATT[((size_t)b*TWOC + j)*CH + c];
  __syncthreads();
  float acc = 0.f;
  if (j < CH) {
    for (int d = 0; d < CH; d++) acc = fmaf(acol[d], v2w[(size_t)d*CH + j], acc);
  } else {
    const int jj = j - CH;
    for (int d = 0; d < CH; d++) acc = fmaf(acol[CH + d], v1w[(size_t)d*CH + jj], acc);
  }
  M[((size_t)b*CH + c)*TWOC + j] = acc;
  if (j == 0) {
    float s = 0.f;
    for (int d = 0; d < CH; d++) s += acol[d]*v2b[d] + acol[CH+d]*v1b[d];
    C0[b*CH + c] = s;
  }
}

__global__ __launch_bounds__(256) void out_kernel(
    const float* __restrict__ x, const float* __restrict__ y,
    const float* __restrict__ M, const float* __restrict__ C0,
    float* __restrict__ out)
{
  const int b  = blockIdx.y;
  const int n0 = blockIdx.x * 64;
  const int tid = threadIdx.x;
  const int tc = tid & 15;
  const int tn = tid >> 4;

  __shared__ __align__(16) float Ms[64][128];
  __shared__ __align__(16) float Zs[64][64];

  float acc[8][4];
  #pragma unroll
  for (int i = 0; i < 8; i++)
    #pragma unroll
    for (int j = 0; j < 4; j++) acc[i][j] = 0.f;

  const float* Mb = M + (size_t)b * CH * TWOC;

  for (int chunk = 0; chunk < 4; chunk++) {
    const int kbase = chunk * 64;
    const float* Zsrc = ((chunk < 2) ? y : x) + (size_t)b * CH * NPTS
                        + (size_t)((chunk & 1) * 64) * NPTS;
    __syncthreads();
    {
      const int c   = tid >> 1;
      const int kb2 = (tid & 1) * 32;
      const float* mr = Mb + (size_t)c * TWOC + kbase + kb2;
      #pragma unroll
      for (int q = 0; q < 8; q++) {
        const float4 v = *(const float4*)(mr + q*4);
        Ms[kb2 + q*4 + 0][c] = v.x;
        Ms[kb2 + q*4 + 1][c] = v.y;
        Ms[kb2 + q*4 + 2][c] = v.z;
        Ms[kb2 + q*4 + 3][c] = v.w;
      }
      const int kk  = tid >> 2;
      const int nb4 = (tid & 3) * 4;
      const float* zr = Zsrc + (size_t)kk * NPTS + n0 + nb4;
      #pragma unroll
      for (int q = 0; q < 4; q++)
        *(float4*)&Zs[kk][nb4 + q*16] = *(const float4*)(zr + q*16);
    }
    __syncthreads();
    #pragma unroll 8
    for (int kk = 0; kk < 64; kk++) {
      float a[8], zz[4];
      *(float4*)&a[0]  = *(const float4*)&Ms[kk][tc*8];
      *(float4*)&a[4]  = *(const float4*)&Ms[kk][tc*8+4];
      *(float4*)&zz[0] = *(const float4*)&Zs[kk][tn*4];
      #pragma unroll
      for (int ii = 0; ii < 8; ii++)
        #pragma unroll
        for (int jj = 0; jj < 4; jj++)
          acc[ii][jj] = fmaf(a[ii], zz[jj], acc[ii][jj]);
    }
  }

  #pragma unroll
  for (int ii = 0; ii < 8; ii++) {
    const int c = tc*8 + ii;
    const float cv = C0[b*CH + c];
    float4 o;
    o.x = acc[ii][0] + cv; o.y = acc[ii][1] + cv;
    o.z = acc[ii][2] + cv; o.w = acc[ii][3] + cv;
    *(float4*)&out[((size_t)b*CH + c)*NPTS + n0 + tn*4] = o;
  }
}

// -----------------------------------------------------------------
extern "C" void kernel_launch(void* const* d_in, const int* in_sizes, int n_in,
                              void* d_out, int out_size, void* d_ws, size_t ws_size,
                              hipStream_t stream)
{
  const float* x   = (const float*)d_in[0];
  const float* y   = (const float*)d_in[1];
  const float* qw  = (const float*)d_in[2];
  const float* qb  = (const float*)d_in[3];
  const float* kw  = (const float*)d_in[4];
  const float* kb  = (const float*)d_in[5];
  const float* v1w = (const float*)d_in[6];
  const float* v1b = (const float*)d_in[7];
  const float* v2w = (const float*)d_in[8];
  const float* v2b = (const float*)d_in[9];
  const float* t1w = (const float*)d_in[10];
  const float* t1b = (const float*)d_in[11];
  const float* t2w = (const float*)d_in[12];
  const float* t2b = (const float*)d_in[13];

  float* ws = (float*)d_ws;
  float* G    = ws + OFF_G;
  float* S    = ws + OFF_S;
  float* P    = ws + OFF_P;
  float* wqkT = ws + OFF_WQKT;
  float* t1wT = ws + OFF_T1T;
  float* t2wT = ws + OFF_T2T;
  float* AT   = ws + OFF_AT;
  float* C0   = ws + OFF_C0;
  float* outp = (float*)d_out;

  // zero G and S
  hipMemsetAsync(d_ws, 0, (OFF_S + 2048) * sizeof(float), stream);

  if (ws_size >= WS_NEED_NEW) {
    _Float16* Mh = (_Float16*)(ws + OFF_MH);
    _Float16* Zh = (_Float16*)(ws + OFF_ZH);
    const bool useGP = (ws_size >= WS_NEED_V3);
    float* GP = useGP ? (ws + OFF_GP) : nullptr;

    wtrans_kernel <<<dim3(640),                 256, 0, stream>>>(qw, kw, t1w, t2w,
                                                                  wqkT, t1wT, t2wT);
    convert_kernel<<<dim3(NPTS/4096, TWOC, NB), 256, 0, stream>>>(x, y, Zh, S);
    gram_mfma3    <<<dim3(3 * NCHUNK * NB),     256, 0, stream>>>(Zh, G, GP);
    if (useGP)
      greduce_kernel<<<dim3(64, 3, NB),         256, 0, stream>>>(GP, G);
    else
      pmirror_kernel<<<dim3(NB),                256, 0, stream>>>(G);
    p_kernel      <<<dim3(NB),                  256, 0, stream>>>(S, qw, kw, P);
    he_att_kernel <<<dim3(32, NB),              256, 0, stream>>>(G, P, qw, kw, qb, kb,
                                                                  wqkT, t1wT, t2wT,
                                                                  t1b, t2b, AT);
    mout_f16_kernel<<<dim3(CH, NB),             256, 0, stream>>>(AT, v1w, v2w, v1b, v2b, Mh, C0);
    out_mfma      <<<dim3(NPTS/128, NB),        256, 0, stream>>>(Zh, Mh, C0, outp);
  } else {
    float* Mo = ws + OFF_MH;
    wtrans_kernel <<<dim3(640),            256, 0, stream>>>(qw, kw, t1w, t2w,
                                                             wqkT, t1wT, t2wT);
    gram_kernel   <<<dim3(3, NPTS/KC, NB), 256, 0, stream>>>(x, y, G, S);
    pmirror_kernel<<<dim3(NB),             256, 0, stream>>>(G);
    p_kernel      <<<dim3(NB),             256, 0, stream>>>(S, qw, kw, P);
    he_att_kernel <<<dim3(32, NB),         256, 0, stream>>>(G, P, qw, kw, qb, kb,
                                                             wqkT, t1wT, t2wT,
                                                             t1b, t2b, AT);
    mout_f32_kernel<<<dim3(CH, NB),        256, 0, stream>>>(AT, v1w, v2w, v1b, v2b, Mo, C0);
    out_kernel    <<<dim3(NPTS/64, NB),    256, 0, stream>>>(x, y, Mo, C0, outp);
  }
}